// Round 3
// baseline (1017.170 us; speedup 1.0000x reference)
//
#include <hip/hip_runtime.h>
#include <hip/hip_bf16.h>
#include <math.h>

#define HW 16384

__device__ __forceinline__ float LD(const void* p, long i, int bf){
  return bf ? __bfloat162float(((const __hip_bfloat16*)p)[i]) : ((const float*)p)[i];
}
__device__ __forceinline__ float geluf(float x){ return 0.5f*x*(1.0f + erff(x*0.70710678118654752f)); }

// ---- ws layout (float offsets) ----
#define OFF_M    0            // Mq(1024) Mk(1024) Mv(1024)
#define OFF_G    3072         // 4 batches * 3 mats * 256 -> zeroed each launch
#define OFF_MB   6144         // 4 * 16*64
#define OFF_FLAG 10240        // int flag: 1 = inputs are bf16, 0 = fp32
#define OFF_QDIM 16384
#define OFF_KDIM (16384 + 1048576)
#define OFF_VDIM (16384 + 2*1048576)
#define OFF_QMIX (16384 + 3*1048576)
#define OFF_KMIX (16384 + 4*1048576)
#define OFF_VMIX (16384 + 5*1048576)
#define OFF_S    (16384 + 6*1048576)
#define FSZ 532480            // 4*16*128*65
// M96 channels-last [b][4096][96] reuses OFF_S (FFT buffers dead by then)

// K-1: dtype flag + zero atomic accumulators
__global__ void k_flag(const void* bng, float* ws){
  int t=threadIdx.x;
  for(int i=3072+t;i<10240;i+=256) ws[i]=0.f;
  if(t==0){
    float v = ((const float*)bng)[0];
    ((int*)ws)[OFF_FLAG] = (v==1.0f) ? 0 : 1;
  }
}

// K0: Mq/Mk/Mv = W{q,k,v} @ Wr   [64,512]@[512,16] -> [64,16]
__global__ void k_fold(const void* Wq, const void* Wk, const void* Wv,
                       const void* Wr, float* ws, const int* flg){
  int bf=*flg;
  const void* Wsrc = blockIdx.x==0 ? Wq : (blockIdx.x==1 ? Wk : Wv);
  float* dst = ws + blockIdx.x*1024;
  __shared__ float wr[512*16];
  for(int i=threadIdx.x;i<8192;i+=256) wr[i]=LD(Wr,i,bf);
  __syncthreads();
  for(int o=threadIdx.x;o<1024;o+=256){
    int c=o>>4, r=o&15; float acc=0.f;
    for(int j=0;j<512;j++) acc += LD(Wsrc,(long)c*512+j,bf)*wr[j*16+r];
    dst[o]=acc;
  }
}

// K1: q/k/v_dim[b,n,r] = x[b,n,:] @ M{q,k,v}
__global__ void k_dims(const void* x, const float* ws,
                       float* qd, float* kd, float* vd, const int* flg){
  int bf=*flg;
  __shared__ float xs[16*64];
  __shared__ float ms[3*1024];
  int b = blockIdx.x>>10;
  int pix0 = (blockIdx.x & 1023)<<4;
  int t = threadIdx.x;
  for(int i=t;i<3072;i+=256) ms[i]=ws[i];
  long base = ((long)b*HW + pix0)*64;
  for(int i=t;i<1024;i+=256) xs[i]=LD(x, base+i, bf);
  __syncthreads();
  int p=t>>4, r=t&15;
  float aq=0.f,ak=0.f,av=0.f;
  for(int c=0;c<64;c++){
    float xv = xs[p*64+c];
    aq += xv*ms[c*16+r];
    ak += xv*ms[1024+c*16+r];
    av += xv*ms[2048+c*16+r];
  }
  long o = ((long)b*HW + pix0)*16 + t;
  qd[o]=aq; kd[o]=ak; vd[o]=av;
}

// K2: SpitialUnit: q_mix = q_dim + gamma * pw(gelu(dw3x3(q_dim)))
__global__ void k_spatial(const float* qd, float* qm, const void* dw,
                          const void* pw, const void* gamma, const int* flg){
  int bf=*flg;
  __shared__ float tile[3*128*16];
  __shared__ float dws[144], pws[256], gs[16];
  int b = blockIdx.x>>7, y = blockIdx.x&127;
  int t = threadIdx.x; // 128
  for(int i=t;i<144;i+=128) dws[i]=LD(dw,i,bf);
  for(int i=t;i<256;i+=128) pws[i]=LD(pw,i,bf);
  if(t<16) gs[t]=LD(gamma,t,bf);
  for(int i=t;i<6144;i+=128){
    int ry = i/2048, rem = i%2048;
    int yy = y-1+ry;
    tile[i] = (yy>=0 && yy<128) ? qd[(long)(b*128+yy)*2048 + rem] : 0.f;
  }
  __syncthreads();
  int x=t;
  float g[16];
  for(int ch=0;ch<16;ch++){
    float acc=0.f;
    for(int p=0;p<3;p++)
      for(int q=0;q<3;q++){
        int xx=x-1+q;
        if(xx>=0&&xx<128) acc += dws[ch*9+p*3+q]*tile[(p*128+xx)*16+ch];
      }
    g[ch]=geluf(acc);
  }
  long ob = ((long)(b*128+y)*128 + x)*16;
  for(int c=0;c<16;c++){
    float acc=0.f;
    for(int ch=0;ch<16;ch++) acc += pws[c*16+ch]*g[ch];
    qm[ob+c] = tile[(128+x)*16+c] + gs[c]*acc;
  }
}

#define MAKE_TWIDDLE(ct,st) { int tt=threadIdx.x; if(tt<128){ float ang = 6.283185307179586f*(float)tt/128.f; float s_,c_; sincosf(ang,&s_,&c_); ct[tt]=c_; st[tt]=s_; } }

// F1: per (b,c,y) row rfft over x -> R[bc, v, y]
__global__ void k_fft_row(const float* kd, float* Rre, float* Rim){
  __shared__ float row[128], ct[128], st[128];
  int blk=blockIdx.x; int y=blk&127; int bc=blk>>7;
  int b=bc>>4, c=bc&15;
  int t=threadIdx.x;
  MAKE_TWIDDLE(ct,st);
  row[t] = kd[((long)(b*128+y)*128+t)*16+c];
  __syncthreads();
  if(t<65){
    float re=0.f, im=0.f;
    for(int x=0;x<128;x++){
      float v=row[x]; int idx=(t*x)&127;
      re += v*ct[idx]; im -= v*st[idx];
    }
    long o = ((long)bc*65+t)*128 + y;
    Rre[o]=re; Rim[o]=im;
  }
}

// F2: per (b,c,v) full fft over y, scale 1/128 (ortho fwd), emit amp/phase [b,c,u,v]
__global__ void k_fft_col(const float* Rre, const float* Rim, float* amp, float* ph){
  __shared__ float rre[128], rim[128], ct[128], st[128];
  int blk=blockIdx.x; int v=blk%65; int bc=blk/65;
  int t=threadIdx.x;
  MAKE_TWIDDLE(ct,st);
  long ib = ((long)bc*65+v)*128;
  rre[t]=Rre[ib+t]; rim[t]=Rim[ib+t];
  __syncthreads();
  float re=0.f, im=0.f;
  for(int y=0;y<128;y++){
    int idx=(t*y)&127;
    float c_=ct[idx], s_=st[idx];
    re += rre[y]*c_ + rim[y]*s_;
    im += rim[y]*c_ - rre[y]*s_;
  }
  re *= (1.f/128.f); im *= (1.f/128.f);
  long o = ((long)bc*128+t)*65+v;
  amp[o]=sqrtf(re*re+im*im);
  ph[o]=atan2f(im,re);
}

// F3: per (b,u,v) pixel: masked amp pointwise + gelu (lo/hi), phase pointwise
__global__ void k_four_pw(const float* amp, const float* ph, float* glo, float* ghi, float* pho,
                          const void* alpw, const void* ahpw,
                          const void* phpw, const void* phs, const int* flg){
  int bf=*flg;
  __shared__ float wl[256], wh[256], wp[256];
  int t=threadIdx.x;
  wl[t]=LD(alpw,t,bf); wh[t]=LD(ahpw,t,bf); wp[t]=LD(phpw,t,bf);
  __syncthreads();
  int p = blockIdx.x*256+t; // 33280 exact
  int b = p/8320; int rem=p%8320; int u=rem/65; int v=rem%65;
  float yy=(float)u/127.f, xx=(float)v/64.f;
  float rr=sqrtf(yy*yy+xx*xx);
  float lo = 1.f/(1.f+expf((rr-0.25f)*20.f));
  float hi = 1.f-lo;
  float alv[16], ahv[16], pv[16];
  for(int ch=0;ch<16;ch++){
    long idx=((long)(b*16+ch)*128+u)*65+v;
    float a=amp[idx];
    alv[ch]=a*lo; ahv[ch]=a*hi; pv[ch]=ph[idx];
  }
  float pscale = LD(phs,0,bf);
  for(int c=0;c<16;c++){
    float al=0.f, ah=0.f, pp=0.f;
    for(int ch=0;ch<16;ch++){
      al += wl[c*16+ch]*alv[ch];
      ah += wh[c*16+ch]*ahv[ch];
      pp += wp[c*16+ch]*pv[ch];
    }
    long o=((long)(b*16+c)*128+u)*65+v;
    glo[o]=geluf(al); ghi[o]=geluf(ah); pho[o]=pv[c]+pscale*pp;
  }
}

// F4: depthwise 3x3 on lo/hi branches, Y = amp_out * e^{i phase_out}, layout [b,c,v,u]
__global__ void k_four_dw(const float* glo, const float* ghi, const float* pho,
                          float* Yre, float* Yim,
                          const void* aldw, const void* ahdw, const int* flg){
  int bf=*flg;
  __shared__ float wl[144], wh[144];
  int t=threadIdx.x;
  if(t<144){wl[t]=LD(aldw,t,bf); wh[t]=LD(ahdw,t,bf);}
  __syncthreads();
  long p = (long)blockIdx.x*256+t;  // 532480 exact
  int v = (int)(p%65); long r1=p/65; int u=(int)(r1%128); int bc=(int)(r1/128); int c=bc&15;
  float acc=0.f;
  for(int dp=0;dp<3;dp++){
    int uu=u-1+dp; if(uu<0||uu>=128) continue;
    for(int dq=0;dq<3;dq++){
      int vv=v-1+dq; if(vv<0||vv>=65) continue;
      long idx=((long)bc*128+uu)*65+vv;
      acc += wl[c*9+dp*3+dq]*glo[idx] + wh[c*9+dp*3+dq]*ghi[idx];
    }
  }
  float pvv = pho[((long)bc*128+u)*65+v];
  float s_,c_; sincosf(pvv,&s_,&c_);
  long o = ((long)bc*65+v)*128+u;
  Yre[o]=acc*c_; Yim[o]=acc*s_;
}

// I1: per (b,c,v): inverse fft over u (e^{+i}), unscaled; Z layout [b,c,y,v]
__global__ void k_ifft_col(const float* Yre, const float* Yim, float* Zre, float* Zim){
  __shared__ float yre[128], yim[128], ct[128], st[128];
  int blk=blockIdx.x; int v=blk%65; int bc=blk/65;
  int t=threadIdx.x;
  MAKE_TWIDDLE(ct,st);
  long ib=((long)bc*65+v)*128;
  yre[t]=Yre[ib+t]; yim[t]=Yim[ib+t];
  __syncthreads();
  float re=0.f,im=0.f;
  for(int u=0;u<128;u++){
    int idx=(t*u)&127; float c_=ct[idx], s_=st[idx];
    re += yre[u]*c_ - yim[u]*s_;
    im += yim[u]*c_ + yre[u]*s_;
  }
  long o=((long)bc*128+t)*65+v;
  Zre[o]=re; Zim[o]=im;
}

// I2: per (b,c,y): hermitian irfft over v (65->128), total scale 1/128, write k_mix NHWC
__global__ void k_ifft_row(const float* Zre, const float* Zim, float* km){
  __shared__ float zre[65], zim[65], ct[128], st[128];
  int blk=blockIdx.x; int y=blk&127; int bc=blk>>7; int b=bc>>4, c=bc&15;
  int t=threadIdx.x;
  MAKE_TWIDDLE(ct,st);
  long ib=((long)bc*128+y)*65;
  if(t<65){ zre[t]=Zre[ib+t]; zim[t]=Zim[ib+t]; }
  __syncthreads();
  int j=t;
  float acc = zre[0] + ((j&1)? -zre[64] : zre[64]);
  for(int k=1;k<64;k++){
    int idx=(j*k)&127;
    acc += 2.f*(zre[k]*ct[idx] - zim[k]*st[idx]);
  }
  acc *= (1.f/128.f);
  km[((long)(b*128+y)*128+j)*16+c]=acc;
}

// W_A: fused haar + BN + mlp_in (48->96), channels-last m96 [b][4096][96]
// block 192 thr handles 16 half-res pixels (one 16-px run of a row)
__global__ void k_wave_a(const float* vd, float* m96, const void* win,
                         const void* bng, const void* bnb, const int* flg){
  int bf=*flg;
  __shared__ float wi[4608];   // [96][48]
  __shared__ float vds[1024];  // 2 rows x 32 cols x 16 ch
  __shared__ float ns[768];    // 16 px x 48
  __shared__ float gs[48], bs[48];
  int t=threadIdx.x; // 192
  int b = blockIdx.x>>8;
  int ij0 = (blockIdx.x&255)<<4;
  for(int i=t;i<4608;i+=192) wi[i]=LD(win,i,bf);
  if(t<48){ gs[t]=LD(bng,t,bf)*(1.f/sqrtf(1.f+1e-5f)); bs[t]=LD(bnb,t,bf); }
  int i0 = ij0>>6, j0 = ij0&63;
  long rb0 = ((long)(b*128 + 2*i0)*128 + 2*j0)*16;
  for(int i=t;i<512;i+=192){ vds[i]=vd[rb0+i]; vds[512+i]=vd[rb0+2048+i]; }
  __syncthreads();
  for(int o=t;o<768;o+=192){
    int p=o/48, cc2=o%48;
    int m=cc2+16, c=m>>2, f=m&3;
    float a =vds[(2*p)*16+c],     bv=vds[(2*p+1)*16+c];
    float cv=vds[512+(2*p)*16+c], dv=vds[512+(2*p+1)*16+c];
    float v;
    if(f==0)      v=(a+bv+cv+dv);
    else if(f==1) v=(a-bv+cv-dv);
    else if(f==2) v=(a+bv-cv-dv);
    else          v=(a-bv-cv+dv);
    ns[o] = v*0.5f*gs[cc2]+bs[cc2];
  }
  __syncthreads();
  long ob = ((long)b*4096 + ij0)*96;
  for(int o=t;o<1536;o+=192){
    int p=o/96, ch=o%96;
    float acc=0.f;
    for(int cc=0;cc<48;cc++) acc += wi[ch*48+cc]*ns[p*48+cc];
    m96[ob+o]=acc;
  }
}

// W_B: fused dw3x3+gelu + mlp_out(96->48) + residual(haar recompute) + IWT
// block 256 thr = 16x16 half-res tile; grid 4b x 16 tiles
__global__ void k_wave_b(const float* m96, const float* vd, float* vm,
                         const void* wdw_, const void* wout_, const void* rs_,
                         const int* flg){
  int bf=*flg;
  __shared__ float wdw[864];    // [96][9]
  __shared__ float wout[4608];  // [48][96]
  __shared__ float ob[16384];   // [256 px][4 pos][16 ch]
  int t=threadIdx.x; //256
  int b=blockIdx.x>>4; int tile=blockIdx.x&15;
  int i0=(tile>>2)<<4, j0=(tile&3)<<4;
  for(int i=t;i<864;i+=256) wdw[i]=LD(wdw_,i,bf);
  for(int i=t;i<4608;i+=256) wout[i]=LD(wout_,i,bf);
  __syncthreads();
  int ti=t>>4, tj=t&15;
  int i=i0+ti, j=j0+tj;
  float g[96];
  long mb = (long)b*4096*96;
  #pragma unroll
  for(int ch=0;ch<96;ch++){
    float s=0.f;
    for(int dp=0;dp<3;dp++){ int ii=i-1+dp; if(ii<0||ii>=64) continue;
      for(int dq=0;dq<3;dq++){ int jj=j-1+dq; if(jj<0||jj>=64) continue;
        s += wdw[ch*9+dp*3+dq]*m96[mb + (long)(ii*64+jj)*96 + ch]; } }
    g[ch]=geluf(s);
  }
  float rs=LD(rs_,0,bf);
  long vb = ((long)(b*128+2*i)*128 + 2*j)*16;
  float* obt = ob + t*64;
  for(int cc=0;cc<48;cc++){
    float acc=0.f;
    #pragma unroll
    for(int ch=0;ch<96;ch++) acc += wout[cc*96+ch]*g[ch];
    int m=cc+16, c=m>>2, f=m&3;
    float a =vd[vb+c],      bv=vd[vb+16+c];
    float cv=vd[vb+2048+c], dv=vd[vb+2048+16+c];
    float hv;
    if(f==0)      hv=(a+bv+cv+dv);
    else if(f==1) hv=(a-bv+cv-dv);
    else if(f==2) hv=(a+bv-cv-dv);
    else          hv=(a-bv-cv+dv);
    hv*=0.5f;
    float he = hv + rs*acc;
    int ff=cc>>4, c16=cc&15;
    int pos = (ff==0)?1:((ff==1)?2:3);
    obt[pos*16+c16]=he;
  }
  for(int c16=0;c16<16;c16++){
    int c=c16>>2, f=c16&3;
    float a =vd[vb+c],      bv=vd[vb+16+c];
    float cv=vd[vb+2048+c], dv=vd[vb+2048+16+c];
    float hv;
    if(f==0)      hv=(a+bv+cv+dv);
    else if(f==1) hv=(a-bv+cv-dv);
    else if(f==2) hv=(a+bv-cv-dv);
    else          hv=(a-bv-cv+dv);
    obt[c16]=hv*0.5f;
  }
  __syncthreads();
  // cooperative coalesced write: 32 rows x 32 cols x 16 ch
  long outb = ((long)(b*128+2*i0)*128 + 2*j0)*16;
  for(int idx=t;idx<16384;idx+=256){
    int orow=idx>>9; int rem=idx&511; int ocol=rem>>4; int c=rem&15;
    int sti=orow>>1, stj=ocol>>1, pos=((orow&1)<<1)|(ocol&1);
    vm[outb + (long)orow*2048 + ocol*16 + c] = ob[(sti*16+stj)*64 + pos*16 + c];
  }
}

// A1: per-batch Gram matrices Gkq, Gkk, Gqq [16,16]
__global__ void k_gram(const float* qm, const float* km, float* G){
  __shared__ float qs[256*16], ks[256*16];
  int b=blockIdx.x>>3; int chunk=blockIdx.x&7;
  int t=threadIdx.x; int r=t>>4, s=t&15;
  float akq=0.f, akk=0.f, aqq=0.f;
  for(int tile=0;tile<8;tile++){
    long pb=((long)b*HW + chunk*2048 + tile*256)*16;
    for(int i=t;i<4096;i+=256){ qs[i]=qm[pb+i]; ks[i]=km[pb+i]; }
    __syncthreads();
    for(int p=0;p<256;p++){
      float kv=ks[p*16+r], qv=qs[p*16+s];
      akq += kv*qv;
      akk += kv*ks[p*16+s];
      aqq += qs[p*16+r]*qv;
    }
    __syncthreads();
  }
  float* Gb=G + b*768;
  atomicAdd(&Gb[t], akq);
  atomicAdd(&Gb[256+t], akk);
  atomicAdd(&Gb[512+t], aqq);
}

// A2: per (b,h): attn from Gram, softmax, fold into M_b[16,64]
__global__ void k_attn(const float* G, float* Mb, const void* We,
                       const void* Wproj, const void* resc, const int* flg){
  int bf=*flg;
  __shared__ float wes[16*64];
  __shared__ float gkq[256], gkk[256], gqq[256];
  __shared__ float ukq[64*16], ukk[64*16], uqq[64*16];
  __shared__ float nk[64], nq[64];
  __shared__ float A[64*64];
  __shared__ float T[64*16];
  __shared__ float wpj[64*64];
  int b=blockIdx.x>>3, h=blockIdx.x&7;
  int t=threadIdx.x;
  for(int i=t;i<1024;i+=256){ int rr=i>>6, e=i&63; wes[rr*64+e]=LD(We, (long)rr*512 + h*64 + e, bf); }
  gkq[t]=G[b*768+t]; gkk[t]=G[b*768+256+t]; gqq[t]=G[b*768+512+t];
  for(int i=t;i<4096;i+=256){ int d=i>>6, c=i&63; wpj[i]=LD(Wproj,(long)(h*64+d)*64+c,bf); }
  __syncthreads();
  for(int i=t;i<1024;i+=256){
    int d=i>>4, s=i&15;
    float a1=0.f,a2=0.f,a3=0.f;
    for(int rr=0;rr<16;rr++){ float wv=wes[rr*64+d]; a1+=wv*gkq[rr*16+s]; a2+=wv*gkk[rr*16+s]; a3+=wv*gqq[rr*16+s]; }
    ukq[i]=a1; ukk[i]=a2; uqq[i]=a3;
  }
  __syncthreads();
  if(t<64){ float a=0.f; for(int s=0;s<16;s++) a+=ukk[t*16+s]*wes[s*64+t]; nk[t]=fmaxf(sqrtf(a),1e-12f); }
  else if(t<128){ int e=t-64; float a=0.f; for(int s=0;s<16;s++) a+=uqq[e*16+s]*wes[s*64+e]; nq[e]=fmaxf(sqrtf(a),1e-12f); }
  __syncthreads();
  float rsc=LD(resc,h,bf);
  for(int i=t;i<4096;i+=256){
    int d=i>>6, e=i&63;
    float a=0.f; for(int s=0;s<16;s++) a+=ukq[d*16+s]*wes[s*64+e];
    A[i]=a/(nk[d]*nq[e])*rsc;
  }
  __syncthreads();
  if(t<64){
    int d=t; float m=-1e30f;
    for(int e=0;e<64;e++) m=fmaxf(m,A[d*64+e]);
    float sum=0.f;
    for(int e=0;e<64;e++){ float ev=expf(A[d*64+e]-m); A[d*64+e]=ev; sum+=ev; }
    float inv=1.f/sum;
    for(int e=0;e<64;e++) A[d*64+e]*=inv;
  }
  __syncthreads();
  for(int i=t;i<1024;i+=256){
    int d=i>>4, s=i&15;
    float a=0.f; for(int e=0;e<64;e++) a+=A[d*64+e]*wes[s*64+e];
    T[i]=a;
  }
  __syncthreads();
  for(int i=t;i<1024;i+=256){
    int s=i>>6, c=i&63;
    float a=0.f; for(int d=0;d<64;d++) a+=T[d*16+s]*wpj[d*64+c];
    atomicAdd(&Mb[b*1024 + s*64 + c], a);
  }
}

// A3: out[b,n,c] = v_mix[b,n,:] @ M_b[:,c] + bproj[c]
__global__ void k_out(const float* vm, const float* Mb, const void* bproj,
                      void* out, const int* flg){
  int bf=*flg;
  long o=(long)blockIdx.x*256+threadIdx.x;
  int c=(int)(o&63); long r=o>>6; int n=(int)(r&16383); int b=(int)(r>>14);
  const float* v=vm + ((long)b*HW+n)*16;
  const float* M=Mb + b*1024;
  float acc=LD(bproj,c,bf);
  for(int s=0;s<16;s++) acc += v[s]*M[s*64+c];
  if(bf) ((__hip_bfloat16*)out)[o]=__float2bfloat16(acc);
  else   ((float*)out)[o]=acc;
}

extern "C" void kernel_launch(void* const* d_in, const int* in_sizes, int n_in,
                              void* d_out, int out_size, void* d_ws, size_t ws_size,
                              hipStream_t stream) {
  const void* x_in   = d_in[0];
  const void* Wq     = d_in[1];
  const void* Wk     = d_in[2];
  const void* Wv     = d_in[3];
  const void* Wr     = d_in[4];
  const void* We     = d_in[5];
  const void* qs_dw  = d_in[6];
  const void* qs_pw  = d_in[7];
  const void* qs_g   = d_in[8];
  const void* al_pw  = d_in[9];
  const void* al_dw  = d_in[10];
  const void* ah_pw  = d_in[11];
  const void* ah_dw  = d_in[12];
  const void* ph_pw  = d_in[13];
  const void* ph_s   = d_in[14];
  const void* bn_g   = d_in[15];
  const void* bn_b   = d_in[16];
  const void* mlp_in = d_in[17];
  const void* mlp_dw = d_in[18];
  const void* mlp_out= d_in[19];
  const void* res_s  = d_in[20];
  const void* rescale= d_in[21];
  const void* Wproj  = d_in[22];
  const void* bproj  = d_in[23];
  float* ws = (float*)d_ws;
  const int* flg = ((const int*)ws) + OFF_FLAG;

  float* FA = ws + OFF_S;
  float* FB = FA + FSZ;
  float* FC = FB + FSZ;
  float* FD = FC + FSZ;
  float* FE = FD + FSZ;
  float* M96 = ws + OFF_S;   // channels-last [b][4096][96]; FFT bufs dead by then

  k_flag<<<1,256,0,stream>>>(bn_g, ws);
  k_fold<<<3,256,0,stream>>>(Wq,Wk,Wv,Wr, ws, flg);
  k_dims<<<4096,256,0,stream>>>(x_in, ws, ws+OFF_QDIM, ws+OFF_KDIM, ws+OFF_VDIM, flg);
  k_spatial<<<512,128,0,stream>>>(ws+OFF_QDIM, ws+OFF_QMIX, qs_dw, qs_pw, qs_g, flg);
  // Fourier branch (k)
  k_fft_row<<<8192,128,0,stream>>>(ws+OFF_KDIM, FA, FB);
  k_fft_col<<<4160,128,0,stream>>>(FA, FB, FC, FD);
  k_four_pw<<<130,256,0,stream>>>(FC, FD, FA, FB, FE, al_pw, ah_pw, ph_pw, ph_s, flg);
  k_four_dw<<<2080,256,0,stream>>>(FA, FB, FE, FC, FD, al_dw, ah_dw, flg);
  k_ifft_col<<<4160,128,0,stream>>>(FC, FD, FA, FB);
  k_ifft_row<<<8192,128,0,stream>>>(FA, FB, ws+OFF_KMIX);
  // Wavelet branch (v), channels-last fused
  k_wave_a<<<1024,192,0,stream>>>(ws+OFF_VDIM, M96, mlp_in, bn_g, bn_b, flg);
  k_wave_b<<<64,256,0,stream>>>(M96, ws+OFF_VDIM, ws+OFF_VMIX, mlp_dw, mlp_out, res_s, flg);
  // Attention (collapsed to Gram matrices)
  k_gram<<<32,256,0,stream>>>(ws+OFF_QMIX, ws+OFF_KMIX, ws+OFF_G);
  k_attn<<<32,256,0,stream>>>(ws+OFF_G, ws+OFF_MB, We, Wproj, rescale, flg);
  k_out<<<16384,256,0,stream>>>(ws+OFF_VMIX, ws+OFF_MB, bproj, d_out, flg);
}

// Round 4
// 584.831 us; speedup vs baseline: 1.7393x; 1.7393x over previous
//
#include <hip/hip_runtime.h>
#include <hip/hip_bf16.h>
#include <math.h>

#define HW 16384

__device__ __forceinline__ float LD(const void* p, long i, int bf){
  return bf ? __bfloat162float(((const __hip_bfloat16*)p)[i]) : ((const float*)p)[i];
}
__device__ __forceinline__ float geluf(float x){ return 0.5f*x*(1.0f + erff(x*0.70710678118654752f)); }

// ---- ws layout (float offsets) ----
#define OFF_M    0            // Mq(1024) Mk(1024) Mv(1024)
#define OFF_G    3072         // zeroed each launch
#define OFF_MB   6144
#define OFF_FLAG 10240        // int flag: 1 = inputs bf16, 0 = fp32
#define OFF_QDIM 16384
#define OFF_KDIM (16384 + 1048576)
#define OFF_VDIM (16384 + 2*1048576)
#define OFF_QMIX (16384 + 3*1048576)
#define OFF_KMIX (16384 + 4*1048576)
#define OFF_VMIX (16384 + 5*1048576)
#define OFF_S    (16384 + 6*1048576)
#define FSZ 532480            // 4*16*128*65

// K-1: dtype flag + zero atomic accumulators
__global__ void k_flag(const void* bng, float* ws){
  int t=threadIdx.x;
  for(int i=3072+t;i<10240;i+=256) ws[i]=0.f;
  if(t==0){
    float v = ((const float*)bng)[0];
    ((int*)ws)[OFF_FLAG] = (v==1.0f) ? 0 : 1;
  }
}

// K0: Mq/Mk/Mv = W{q,k,v} @ Wr
__global__ void k_fold(const void* Wq, const void* Wk, const void* Wv,
                       const void* Wr, float* ws, const int* flg){
  int bf=*flg;
  const void* Wsrc = blockIdx.x==0 ? Wq : (blockIdx.x==1 ? Wk : Wv);
  float* dst = ws + blockIdx.x*1024;
  __shared__ float wr[512*16];
  for(int i=threadIdx.x;i<8192;i+=256) wr[i]=LD(Wr,i,bf);
  __syncthreads();
  for(int o=threadIdx.x;o<1024;o+=256){
    int c=o>>4, r=o&15; float acc=0.f;
    for(int j=0;j<512;j++) acc += LD(Wsrc,(long)c*512+j,bf)*wr[j*16+r];
    dst[o]=acc;
  }
}

// K1: q/k/v_dim[b,n,r] = x[b,n,:] @ M{q,k,v}
__global__ void k_dims(const void* x, const float* ws,
                       float* qd, float* kd, float* vd, const int* flg){
  int bf=*flg;
  __shared__ float xs[16*64];
  __shared__ float ms[3*1024];
  int b = blockIdx.x>>10;
  int pix0 = (blockIdx.x & 1023)<<4;
  int t = threadIdx.x;
  for(int i=t;i<3072;i+=256) ms[i]=ws[i];
  long base = ((long)b*HW + pix0)*64;
  for(int i=t;i<1024;i+=256) xs[i]=LD(x, base+i, bf);
  __syncthreads();
  int p=t>>4, r=t&15;
  float aq=0.f,ak=0.f,av=0.f;
  for(int c=0;c<64;c++){
    float xv = xs[p*64+c];
    aq += xv*ms[c*16+r];
    ak += xv*ms[1024+c*16+r];
    av += xv*ms[2048+c*16+r];
  }
  long o = ((long)b*HW + pix0)*16 + t;
  qd[o]=aq; kd[o]=ak; vd[o]=av;
}

// K2: SpitialUnit (tile stride padded to 17 to kill 32-way LDS conflicts)
__global__ void k_spatial(const float* qd, float* qm, const void* dw,
                          const void* pw, const void* gamma, const int* flg){
  int bf=*flg;
  __shared__ float tile[3*128*17];
  __shared__ float dws[144], pws[256], gs[16];
  int b = blockIdx.x>>7, y = blockIdx.x&127;
  int t = threadIdx.x; // 128
  for(int i=t;i<144;i+=128) dws[i]=LD(dw,i,bf);
  for(int i=t;i<256;i+=128) pws[i]=LD(pw,i,bf);
  if(t<16) gs[t]=LD(gamma,t,bf);
  for(int i=t;i<6144;i+=128){
    int ry = i/2048, rem = i%2048;
    int xx = rem>>4, ch = rem&15;
    int yy = y-1+ry;
    tile[(ry*128+xx)*17+ch] = (yy>=0 && yy<128) ? qd[(long)(b*128+yy)*2048 + rem] : 0.f;
  }
  __syncthreads();
  int x=t;
  float g[16];
  for(int ch=0;ch<16;ch++){
    float acc=0.f;
    for(int p=0;p<3;p++)
      for(int q=0;q<3;q++){
        int xx=x-1+q;
        if(xx>=0&&xx<128) acc += dws[ch*9+p*3+q]*tile[(p*128+xx)*17+ch];
      }
    g[ch]=geluf(acc);
  }
  long ob = ((long)(b*128+y)*128 + x)*16;
  for(int c=0;c<16;c++){
    float acc=0.f;
    for(int ch=0;ch<16;ch++) acc += pws[c*16+ch]*g[ch];
    qm[ob+c] = tile[(128+x)*17+c] + gs[c]*acc;
  }
}

#define MAKE_TWIDDLE(ct,st) { int tt=threadIdx.x; if(tt<128){ float ang = 6.283185307179586f*(float)tt/128.f; float s_,c_; sincosf(ang,&s_,&c_); ct[tt]=c_; st[tt]=s_; } }

// F1: per (b,c,y) row rfft over x -> R[bc, v, y]
__global__ void k_fft_row(const float* kd, float* Rre, float* Rim){
  __shared__ float row[128], ct[128], st[128];
  int blk=blockIdx.x; int y=blk&127; int bc=blk>>7;
  int b=bc>>4, c=bc&15;
  int t=threadIdx.x;
  MAKE_TWIDDLE(ct,st);
  row[t] = kd[((long)(b*128+y)*128+t)*16+c];
  __syncthreads();
  if(t<65){
    float re=0.f, im=0.f;
    for(int x=0;x<128;x++){
      float v=row[x]; int idx=(t*x)&127;
      re += v*ct[idx]; im -= v*st[idx];
    }
    long o = ((long)bc*65+t)*128 + y;
    Rre[o]=re; Rim[o]=im;
  }
}

// F2: per (b,c,v) full fft over y, emit amp/phase [b,c,u,v]
__global__ void k_fft_col(const float* Rre, const float* Rim, float* amp, float* ph){
  __shared__ float rre[128], rim[128], ct[128], st[128];
  int blk=blockIdx.x; int v=blk%65; int bc=blk/65;
  int t=threadIdx.x;
  MAKE_TWIDDLE(ct,st);
  long ib = ((long)bc*65+v)*128;
  rre[t]=Rre[ib+t]; rim[t]=Rim[ib+t];
  __syncthreads();
  float re=0.f, im=0.f;
  for(int y=0;y<128;y++){
    int idx=(t*y)&127;
    float c_=ct[idx], s_=st[idx];
    re += rre[y]*c_ + rim[y]*s_;
    im += rim[y]*c_ - rre[y]*s_;
  }
  re *= (1.f/128.f); im *= (1.f/128.f);
  long o = ((long)bc*128+t)*65+v;
  amp[o]=sqrtf(re*re+im*im);
  ph[o]=atan2f(im,re);
}

// F3: per (b,u,v): masked amp pointwise + gelu (lo/hi), phase pointwise
__global__ void k_four_pw(const float* amp, const float* ph, float* glo, float* ghi, float* pho,
                          const void* alpw, const void* ahpw,
                          const void* phpw, const void* phs, const int* flg){
  int bf=*flg;
  __shared__ float wl[256], wh[256], wp[256];
  int t=threadIdx.x;
  wl[t]=LD(alpw,t,bf); wh[t]=LD(ahpw,t,bf); wp[t]=LD(phpw,t,bf);
  __syncthreads();
  int p = blockIdx.x*256+t; // 33280 exact
  int b = p/8320; int rem=p%8320; int u=rem/65; int v=rem%65;
  float yy=(float)u/127.f, xx=(float)v/64.f;
  float rr=sqrtf(yy*yy+xx*xx);
  float lo = 1.f/(1.f+expf((rr-0.25f)*20.f));
  float hi = 1.f-lo;
  float alv[16], ahv[16], pv[16];
  for(int ch=0;ch<16;ch++){
    long idx=((long)(b*16+ch)*128+u)*65+v;
    float a=amp[idx];
    alv[ch]=a*lo; ahv[ch]=a*hi; pv[ch]=ph[idx];
  }
  float pscale = LD(phs,0,bf);
  for(int c=0;c<16;c++){
    float al=0.f, ah=0.f, pp=0.f;
    for(int ch=0;ch<16;ch++){
      al += wl[c*16+ch]*alv[ch];
      ah += wh[c*16+ch]*ahv[ch];
      pp += wp[c*16+ch]*pv[ch];
    }
    long o=((long)(b*16+c)*128+u)*65+v;
    glo[o]=geluf(al); ghi[o]=geluf(ah); pho[o]=pv[c]+pscale*pp;
  }
}

// F4: depthwise 3x3 lo/hi, Y = amp_out * e^{i phase_out}, layout [b,c,v,u]
__global__ void k_four_dw(const float* glo, const float* ghi, const float* pho,
                          float* Yre, float* Yim,
                          const void* aldw, const void* ahdw, const int* flg){
  int bf=*flg;
  __shared__ float wl[144], wh[144];
  int t=threadIdx.x;
  if(t<144){wl[t]=LD(aldw,t,bf); wh[t]=LD(ahdw,t,bf);}
  __syncthreads();
  long p = (long)blockIdx.x*256+t;  // 532480 exact
  int v = (int)(p%65); long r1=p/65; int u=(int)(r1%128); int bc=(int)(r1/128); int c=bc&15;
  float acc=0.f;
  for(int dp=0;dp<3;dp++){
    int uu=u-1+dp; if(uu<0||uu>=128) continue;
    for(int dq=0;dq<3;dq++){
      int vv=v-1+dq; if(vv<0||vv>=65) continue;
      long idx=((long)bc*128+uu)*65+vv;
      acc += wl[c*9+dp*3+dq]*glo[idx] + wh[c*9+dp*3+dq]*ghi[idx];
    }
  }
  float pvv = pho[((long)bc*128+u)*65+v];
  float s_,c_; sincosf(pvv,&s_,&c_);
  long o = ((long)bc*65+v)*128+u;
  Yre[o]=acc*c_; Yim[o]=acc*s_;
}

// I1: inverse fft over u; Z layout [b,c,y,v]
__global__ void k_ifft_col(const float* Yre, const float* Yim, float* Zre, float* Zim){
  __shared__ float yre[128], yim[128], ct[128], st[128];
  int blk=blockIdx.x; int v=blk%65; int bc=blk/65;
  int t=threadIdx.x;
  MAKE_TWIDDLE(ct,st);
  long ib=((long)bc*65+v)*128;
  yre[t]=Yre[ib+t]; yim[t]=Yim[ib+t];
  __syncthreads();
  float re=0.f,im=0.f;
  for(int u=0;u<128;u++){
    int idx=(t*u)&127; float c_=ct[idx], s_=st[idx];
    re += yre[u]*c_ - yim[u]*s_;
    im += yim[u]*c_ + yre[u]*s_;
  }
  long o=((long)bc*128+t)*65+v;
  Zre[o]=re; Zim[o]=im;
}

// I2: hermitian irfft over v (65->128), write k_mix NHWC
__global__ void k_ifft_row(const float* Zre, const float* Zim, float* km){
  __shared__ float zre[65], zim[65], ct[128], st[128];
  int blk=blockIdx.x; int y=blk&127; int bc=blk>>7; int b=bc>>4, c=bc&15;
  int t=threadIdx.x;
  MAKE_TWIDDLE(ct,st);
  long ib=((long)bc*128+y)*65;
  if(t<65){ zre[t]=Zre[ib+t]; zim[t]=Zim[ib+t]; }
  __syncthreads();
  int j=t;
  float acc = zre[0] + ((j&1)? -zre[64] : zre[64]);
  for(int k=1;k<64;k++){
    int idx=(j*k)&127;
    acc += 2.f*(zre[k]*ct[idx] - zim[k]*st[idx]);
  }
  acc *= (1.f/128.f);
  km[((long)(b*128+y)*128+j)*16+c]=acc;
}

// W_A: fused haar + BN + mlp_in (48->96), channels-last m96 [b][4096][96]
__global__ void k_wave_a(const float* vd, float* m96, const void* win,
                         const void* bng, const void* bnb, const int* flg){
  int bf=*flg;
  __shared__ float wi[4608];   // transposed [cc][ch] (stride 96, conflict-free)
  __shared__ float vds[1024];
  __shared__ float ns[768];
  __shared__ float gs[48], bs[48];
  int t=threadIdx.x; // 192
  int b = blockIdx.x>>8;
  int ij0 = (blockIdx.x&255)<<4;
  for(int i=t;i<4608;i+=192){ int cc=i/96, ch=i%96; wi[cc*96+ch]=LD(win,(long)ch*48+cc,bf); }
  if(t<48){ gs[t]=LD(bng,t,bf)*(1.f/sqrtf(1.f+1e-5f)); bs[t]=LD(bnb,t,bf); }
  int i0 = ij0>>6, j0 = ij0&63;
  long rb0 = ((long)(b*128 + 2*i0)*128 + 2*j0)*16;
  for(int i=t;i<512;i+=192){ vds[i]=vd[rb0+i]; vds[512+i]=vd[rb0+2048+i]; }
  __syncthreads();
  for(int o=t;o<768;o+=192){
    int p=o/48, cc2=o%48;
    int m=cc2+16, c=m>>2, f=m&3;
    float a =vds[(2*p)*16+c],     bv=vds[(2*p+1)*16+c];
    float cv=vds[512+(2*p)*16+c], dv=vds[512+(2*p+1)*16+c];
    float v;
    if(f==0)      v=(a+bv+cv+dv);
    else if(f==1) v=(a-bv+cv-dv);
    else if(f==2) v=(a+bv-cv-dv);
    else          v=(a-bv-cv+dv);
    ns[o] = v*0.5f*gs[cc2]+bs[cc2];
  }
  __syncthreads();
  long ob = ((long)b*4096 + ij0)*96;
  for(int o=t;o<1536;o+=192){
    int p=o/96, ch=o%96;
    float acc=0.f;
    for(int cc=0;cc<48;cc++) acc += wi[cc*96+ch]*ns[p*48+cc];
    m96[ob+o]=acc;
  }
}

// W_DW: depthwise 3x3 + gelu, channels-last, coalesced; grid 6144x256
__global__ void k_wave_dw(const float* m96, float* g96, const void* wdw_, const int* flg){
  int bf=*flg;
  __shared__ float wdw[864];
  int t=threadIdx.x;
  for(int i=t;i<864;i+=256) wdw[i]=LD(wdw_,i,bf);
  __syncthreads();
  int o = blockIdx.x*256+t;   // 1,572,864 exact
  int ch = o%96; int r = o/96; int px = r&4095; int b = r>>12;
  int i = px>>6, j = px&63;
  long mb = (long)b*393216;
  float acc=0.f;
  for(int dp=0;dp<3;dp++){ int ii=i-1+dp; if(ii<0||ii>=64) continue;
    for(int dq=0;dq<3;dq++){ int jj=j-1+dq; if(jj<0||jj>=64) continue;
      acc += wdw[ch*9+dp*3+dq]*m96[mb + (long)(ii*64+jj)*96 + ch]; } }
  g96[o]=geluf(acc);
}

// W_OUT: mlp_out(96->48) + residual haar + IWT interleave, per 8x8 half-res tile
__global__ void k_wave_out(const float* g96, const float* vd, float* vm,
                           const void* wout_, const void* rs_, const int* flg){
  int bf=*flg;
  __shared__ float wt[4608];   // transposed [ch][cc] stride 48
  __shared__ float gt[6144];   // [64 px][96]
  __shared__ float ob[4096];   // [64 px][4 pos][16 ch]
  int t=threadIdx.x; // 256
  int b=blockIdx.x>>6; int tile=blockIdx.x&63;
  int i0=(tile>>3)<<3, j0=(tile&7)<<3;
  for(int i=t;i<4608;i+=256){ int ch=i/48, cc=i%48; wt[ch*48+cc]=LD(wout_,(long)cc*96+ch,bf); }
  for(int i=t;i<6144;i+=256){
    int px=i/96, ch=i%96;
    int gi=i0+(px>>3), gj=j0+(px&7);
    gt[i]=g96[((long)b*4096 + gi*64+gj)*96 + ch];
  }
  __syncthreads();
  float rs=LD(rs_,0,bf);
  // high channels: 64 px * 48 cc
  for(int o=t;o<3072;o+=256){
    int px=o/48, cc=o%48;
    int gi=i0+(px>>3), gj=j0+(px&7);
    float acc=0.f;
    for(int ch=0;ch<96;ch++) acc += wt[ch*48+cc]*gt[px*96+ch];
    long vb = ((long)(b*128+2*gi)*128 + 2*gj)*16;
    int m=cc+16, c=m>>2, f=m&3;
    float a=vd[vb+c], bv=vd[vb+16+c], cv=vd[vb+2048+c], dv=vd[vb+2048+16+c];
    float hv;
    if(f==0)      hv=(a+bv+cv+dv);
    else if(f==1) hv=(a-bv+cv-dv);
    else if(f==2) hv=(a+bv-cv-dv);
    else          hv=(a-bv-cv+dv);
    hv*=0.5f;
    float he = hv + rs*acc;
    int ff=cc>>4, c16=cc&15;
    int pos=(ff==0)?1:((ff==1)?2:3);
    ob[px*64+pos*16+c16]=he;
  }
  // LL: 64 px * 16
  for(int o=t;o<1024;o+=256){
    int px=o>>4, c16=o&15;
    int gi=i0+(px>>3), gj=j0+(px&7);
    long vb=((long)(b*128+2*gi)*128+2*gj)*16;
    int c=c16>>2, f=c16&3;
    float a=vd[vb+c], bv=vd[vb+16+c], cv=vd[vb+2048+c], dv=vd[vb+2048+16+c];
    float hv;
    if(f==0)      hv=(a+bv+cv+dv);
    else if(f==1) hv=(a-bv+cv-dv);
    else if(f==2) hv=(a+bv-cv-dv);
    else          hv=(a-bv-cv+dv);
    ob[px*64+c16]=hv*0.5f;
  }
  __syncthreads();
  // coalesced write: 16 rows x (16 col x 16 ch = 256 contiguous floats)
  long outb = ((long)(b*128+2*i0)*128 + 2*j0)*16;
  for(int idx=t;idx<4096;idx+=256){
    int orow=idx>>8; int rem=idx&255; int ocol=rem>>4; int c=rem&15;
    int sti=orow>>1, stj=ocol>>1, pos=((orow&1)<<1)|(ocol&1);
    vm[outb + (long)orow*2048 + ocol*16 + c] = ob[(sti*8+stj)*64+pos*16+c];
  }
}

// A1: per-batch Gram matrices Gkq, Gkk, Gqq [16,16]; grid 128
__global__ void k_gram(const float* qm, const float* km, float* G){
  __shared__ float qs[256*16], ks[256*16];
  int b=blockIdx.x>>5; int chunk=blockIdx.x&31;
  int t=threadIdx.x; int r=t>>4, s=t&15;
  float akq=0.f, akk=0.f, aqq=0.f;
  for(int tile=0;tile<2;tile++){
    long pb=((long)b*HW + chunk*512 + tile*256)*16;
    for(int i=t;i<4096;i+=256){ qs[i]=qm[pb+i]; ks[i]=km[pb+i]; }
    __syncthreads();
    for(int p=0;p<256;p++){
      float kv=ks[p*16+r], qv=qs[p*16+s];
      akq += kv*qv;
      akk += kv*ks[p*16+s];
      aqq += qs[p*16+r]*qv;
    }
    __syncthreads();
  }
  float* Gb=G + b*768;
  atomicAdd(&Gb[t], akq);
  atomicAdd(&Gb[256+t], akk);
  atomicAdd(&Gb[512+t], aqq);
}

// A2: per (b,h): attn from Gram, softmax, fold into M_b[16,64]
__global__ void k_attn(const float* G, float* Mb, const void* We,
                       const void* Wproj, const void* resc, const int* flg){
  int bf=*flg;
  __shared__ float wes[16*64];
  __shared__ float gkq[256], gkk[256], gqq[256];
  __shared__ float ukq[64*16], ukk[64*16], uqq[64*16];
  __shared__ float nk[64], nq[64];
  __shared__ float A[64*64];
  __shared__ float T[64*16];
  __shared__ float wpj[64*64];
  int b=blockIdx.x>>3, h=blockIdx.x&7;
  int t=threadIdx.x;
  for(int i=t;i<1024;i+=256){ int rr=i>>6, e=i&63; wes[rr*64+e]=LD(We, (long)rr*512 + h*64 + e, bf); }
  gkq[t]=G[b*768+t]; gkk[t]=G[b*768+256+t]; gqq[t]=G[b*768+512+t];
  for(int i=t;i<4096;i+=256){ int d=i>>6, c=i&63; wpj[i]=LD(Wproj,(long)(h*64+d)*64+c,bf); }
  __syncthreads();
  for(int i=t;i<1024;i+=256){
    int d=i>>4, s=i&15;
    float a1=0.f,a2=0.f,a3=0.f;
    for(int rr=0;rr<16;rr++){ float wv=wes[rr*64+d]; a1+=wv*gkq[rr*16+s]; a2+=wv*gkk[rr*16+s]; a3+=wv*gqq[rr*16+s]; }
    ukq[i]=a1; ukk[i]=a2; uqq[i]=a3;
  }
  __syncthreads();
  if(t<64){ float a=0.f; for(int s=0;s<16;s++) a+=ukk[t*16+s]*wes[s*64+t]; nk[t]=fmaxf(sqrtf(a),1e-12f); }
  else if(t<128){ int e=t-64; float a=0.f; for(int s=0;s<16;s++) a+=uqq[e*16+s]*wes[s*64+e]; nq[e]=fmaxf(sqrtf(a),1e-12f); }
  __syncthreads();
  float rsc=LD(resc,h,bf);
  for(int i=t;i<4096;i+=256){
    int d=i>>6, e=i&63;
    float a=0.f; for(int s=0;s<16;s++) a+=ukq[d*16+s]*wes[s*64+e];
    A[i]=a/(nk[d]*nq[e])*rsc;
  }
  __syncthreads();
  if(t<64){
    int d=t; float m=-1e30f;
    for(int e=0;e<64;e++) m=fmaxf(m,A[d*64+e]);
    float sum=0.f;
    for(int e=0;e<64;e++){ float ev=expf(A[d*64+e]-m); A[d*64+e]=ev; sum+=ev; }
    float inv=1.f/sum;
    for(int e=0;e<64;e++) A[d*64+e]*=inv;
  }
  __syncthreads();
  for(int i=t;i<1024;i+=256){
    int d=i>>4, s=i&15;
    float a=0.f; for(int e=0;e<64;e++) a+=A[d*64+e]*wes[s*64+e];
    T[i]=a;
  }
  __syncthreads();
  for(int i=t;i<1024;i+=256){
    int s=i>>6, c=i&63;
    float a=0.f; for(int d=0;d<64;d++) a+=T[d*16+s]*wpj[d*64+c];
    atomicAdd(&Mb[b*1024 + s*64 + c], a);
  }
}

// A3: out[b,n,c] = v_mix[b,n,:] @ M_b[:,c] + bproj[c]
__global__ void k_out(const float* vm, const float* Mb, const void* bproj,
                      void* out, const int* flg){
  int bf=*flg;
  long o=(long)blockIdx.x*256+threadIdx.x;
  int c=(int)(o&63); long r=o>>6; int n=(int)(r&16383); int b=(int)(r>>14);
  const float* v=vm + ((long)b*HW+n)*16;
  const float* M=Mb + b*1024;
  float acc=LD(bproj,c,bf);
  for(int s=0;s<16;s++) acc += v[s]*M[s*64+c];
  if(bf) ((__hip_bfloat16*)out)[o]=__float2bfloat16(acc);
  else   ((float*)out)[o]=acc;
}

extern "C" void kernel_launch(void* const* d_in, const int* in_sizes, int n_in,
                              void* d_out, int out_size, void* d_ws, size_t ws_size,
                              hipStream_t stream) {
  const void* x_in   = d_in[0];
  const void* Wq     = d_in[1];
  const void* Wk     = d_in[2];
  const void* Wv     = d_in[3];
  const void* Wr     = d_in[4];
  const void* We     = d_in[5];
  const void* qs_dw  = d_in[6];
  const void* qs_pw  = d_in[7];
  const void* qs_g   = d_in[8];
  const void* al_pw  = d_in[9];
  const void* al_dw  = d_in[10];
  const void* ah_pw  = d_in[11];
  const void* ah_dw  = d_in[12];
  const void* ph_pw  = d_in[13];
  const void* ph_s   = d_in[14];
  const void* bn_g   = d_in[15];
  const void* bn_b   = d_in[16];
  const void* mlp_in = d_in[17];
  const void* mlp_dw = d_in[18];
  const void* mlp_out= d_in[19];
  const void* res_s  = d_in[20];
  const void* rescale= d_in[21];
  const void* Wproj  = d_in[22];
  const void* bproj  = d_in[23];
  float* ws = (float*)d_ws;
  const int* flg = ((const int*)ws) + OFF_FLAG;

  float* FA = ws + OFF_S;
  float* FB = FA + FSZ;
  float* FC = FB + FSZ;
  float* FD = FC + FSZ;
  float* FE = FD + FSZ;
  float* M96 = ws + OFF_S;             // [b][4096][96]; FFT bufs dead by then
  float* G96 = ws + OFF_S + 1572864;

  k_flag<<<1,256,0,stream>>>(bn_g, ws);
  k_fold<<<3,256,0,stream>>>(Wq,Wk,Wv,Wr, ws, flg);
  k_dims<<<4096,256,0,stream>>>(x_in, ws, ws+OFF_QDIM, ws+OFF_KDIM, ws+OFF_VDIM, flg);
  k_spatial<<<512,128,0,stream>>>(ws+OFF_QDIM, ws+OFF_QMIX, qs_dw, qs_pw, qs_g, flg);
  // Fourier branch (k)
  k_fft_row<<<8192,128,0,stream>>>(ws+OFF_KDIM, FA, FB);
  k_fft_col<<<4160,128,0,stream>>>(FA, FB, FC, FD);
  k_four_pw<<<130,256,0,stream>>>(FC, FD, FA, FB, FE, al_pw, ah_pw, ph_pw, ph_s, flg);
  k_four_dw<<<2080,256,0,stream>>>(FA, FB, FE, FC, FD, al_dw, ah_dw, flg);
  k_ifft_col<<<4160,128,0,stream>>>(FC, FD, FA, FB);
  k_ifft_row<<<8192,128,0,stream>>>(FA, FB, ws+OFF_KMIX);
  // Wavelet branch (v), channels-last
  k_wave_a<<<1024,192,0,stream>>>(ws+OFF_VDIM, M96, mlp_in, bn_g, bn_b, flg);
  k_wave_dw<<<6144,256,0,stream>>>(M96, G96, mlp_dw, flg);
  k_wave_out<<<256,256,0,stream>>>(G96, ws+OFF_VDIM, ws+OFF_VMIX, mlp_out, res_s, flg);
  // Attention (collapsed to Gram matrices)
  k_gram<<<128,256,0,stream>>>(ws+OFF_QMIX, ws+OFF_KMIX, ws+OFF_G);
  k_attn<<<32,256,0,stream>>>(ws+OFF_G, ws+OFF_MB, We, Wproj, rescale, flg);
  k_out<<<16384,256,0,stream>>>(ws+OFF_VMIX, ws+OFF_MB, bproj, d_out, flg);
}

// Round 5
// 498.634 us; speedup vs baseline: 2.0399x; 1.1729x over previous
//
#include <hip/hip_runtime.h>
#include <hip/hip_bf16.h>
#include <math.h>

#define HW 16384

__device__ __forceinline__ float LD(const void* p, long i, int bf){
  return bf ? __bfloat162float(((const __hip_bfloat16*)p)[i]) : ((const float*)p)[i];
}
__device__ __forceinline__ float geluf(float x){ return 0.5f*x*(1.0f + erff(x*0.70710678118654752f)); }
__device__ __forceinline__ int rev7(int i){ return (int)(__brev((unsigned)i)>>25); }

// In-wave 128-pt radix-2 FFT: 64 lanes = 64 butterflies/stage, in-place in LDS,
// wave-lockstep => no syncthreads. dir=-1 fwd (e^{-i}), +1 inv (e^{+i}).
__device__ __forceinline__ void fft128(float* Ar, float* Ai, const float* ct, const float* st,
                                       int lane, float dir){
  #pragma unroll
  for(int len=2; len<=128; len<<=1){
    int half=len>>1;
    int pos = lane & (half-1);
    int i1 = ((lane & ~(half-1))<<1) | pos;
    int i2 = i1 + half;
    int tw = pos * (128/len);
    float wr = ct[tw], wi = dir*st[tw];
    float xr=Ar[i2], xi=Ai[i2];
    float tr = xr*wr - xi*wi;
    float ti = xr*wi + xi*wr;
    float ur=Ar[i1], ui=Ai[i1];
    Ar[i1]=ur+tr; Ai[i1]=ui+ti;
    Ar[i2]=ur-tr; Ai[i2]=ui-ti;
  }
}

#define MAKE_TW(ct,st) { int tt=threadIdx.x; if(tt<128){ float ang=6.283185307179586f*(float)tt/128.f; float s_,c_; sincosf(ang,&s_,&c_); ct[tt]=c_; st[tt]=s_; } }

// ---- ws layout (float offsets) ----
#define OFF_M    0
#define OFF_G    3072
#define OFF_MB   6144
#define OFF_FLAG 10240
#define OFF_QDIM 16384
#define OFF_KDIM (16384 + 1048576)
#define OFF_VDIM (16384 + 2*1048576)
#define OFF_QMIX (16384 + 3*1048576)
#define OFF_KMIX (16384 + 4*1048576)
#define OFF_VMIX (16384 + 5*1048576)   // unused now
#define OFF_S    (16384 + 6*1048576)
#define FSZ 532480            // 4*128*65*16

__global__ void k_flag(const void* bng, float* ws){
  int t=threadIdx.x;
  for(int i=3072+t;i<10240;i+=256) ws[i]=0.f;
  if(t==0){
    float v = ((const float*)bng)[0];
    ((int*)ws)[OFF_FLAG] = (v==1.0f) ? 0 : 1;
  }
}

__global__ void k_fold(const void* Wq, const void* Wk, const void* Wv,
                       const void* Wr, float* ws, const int* flg){
  int bf=*flg;
  const void* Wsrc = blockIdx.x==0 ? Wq : (blockIdx.x==1 ? Wk : Wv);
  float* dst = ws + blockIdx.x*1024;
  __shared__ float wr[512*16];
  for(int i=threadIdx.x;i<8192;i+=256) wr[i]=LD(Wr,i,bf);
  __syncthreads();
  for(int o=threadIdx.x;o<1024;o+=256){
    int c=o>>4, r=o&15; float acc=0.f;
    for(int j=0;j<512;j++) acc += LD(Wsrc,(long)c*512+j,bf)*wr[j*16+r];
    dst[o]=acc;
  }
}

__global__ void k_dims(const void* x, const float* ws,
                       float* qd, float* kd, float* vd, const int* flg){
  int bf=*flg;
  __shared__ float xs[16*64];
  __shared__ float ms[3*1024];
  int b = blockIdx.x>>10;
  int pix0 = (blockIdx.x & 1023)<<4;
  int t = threadIdx.x;
  for(int i=t;i<3072;i+=256) ms[i]=ws[i];
  long base = ((long)b*HW + pix0)*64;
  for(int i=t;i<1024;i+=256) xs[i]=LD(x, base+i, bf);
  __syncthreads();
  int p=t>>4, r=t&15;
  float aq=0.f,ak=0.f,av=0.f;
  for(int c=0;c<64;c++){
    float xv = xs[p*64+c];
    aq += xv*ms[c*16+r];
    ak += xv*ms[1024+c*16+r];
    av += xv*ms[2048+c*16+r];
  }
  long o = ((long)b*HW + pix0)*16 + t;
  qd[o]=aq; kd[o]=ak; vd[o]=av;
}

__global__ void k_spatial(const float* qd, float* qm, const void* dw,
                          const void* pw, const void* gamma, const int* flg){
  int bf=*flg;
  __shared__ float tile[3*128*17];
  __shared__ float dws[144], pws[256], gs[16];
  int b = blockIdx.x>>7, y = blockIdx.x&127;
  int t = threadIdx.x; // 128
  for(int i=t;i<144;i+=128) dws[i]=LD(dw,i,bf);
  for(int i=t;i<256;i+=128) pws[i]=LD(pw,i,bf);
  if(t<16) gs[t]=LD(gamma,t,bf);
  for(int i=t;i<6144;i+=128){
    int ry = i/2048, rem = i%2048;
    int xx = rem>>4, ch = rem&15;
    int yy = y-1+ry;
    tile[(ry*128+xx)*17+ch] = (yy>=0 && yy<128) ? qd[(long)(b*128+yy)*2048 + rem] : 0.f;
  }
  __syncthreads();
  int x=t;
  float g[16];
  for(int ch=0;ch<16;ch++){
    float acc=0.f;
    for(int p=0;p<3;p++)
      for(int q=0;q<3;q++){
        int xx=x-1+q;
        if(xx>=0&&xx<128) acc += dws[ch*9+p*3+q]*tile[(p*128+xx)*17+ch];
      }
    g[ch]=geluf(acc);
  }
  long ob = ((long)(b*128+y)*128 + x)*16;
  for(int c=0;c<16;c++){
    float acc=0.f;
    for(int ch=0;ch<16;ch++) acc += pws[c*16+ch]*g[ch];
    qm[ob+c] = tile[(128+x)*17+c] + gs[c]*acc;
  }
}

// F1: row rfft (radix-2). grid 4b*64yg, 256thr. kd NHWC -> R[b][y][v][c] (re,im)
__global__ void k_fft_row(const float* kd, float* Rre, float* Rim){
  __shared__ float slab[4160];            // [2y][16c][130x]
  __shared__ float outre[2112], outim[2112]; // [2y][16c][66v]
  __shared__ float Ar[512], Ai[512];
  __shared__ float ct[128], st[128];
  int t=threadIdx.x;
  int b = blockIdx.x>>6, y0 = (blockIdx.x&63)<<1;
  MAKE_TW(ct,st);
  long gbase = ((long)(b*128+y0))*2048;
  for(int e=t;e<4096;e+=256){
    int yl=e>>11, rem=e&2047, x=rem>>4, c=rem&15;
    slab[yl*2080 + c*130 + x] = kd[gbase + e];
  }
  __syncthreads();
  int w=t>>6, l=t&63, wb=w<<7;
  for(int li=w; li<32; li+=4){
    int yl=li>>4, c=li&15;
    int sb = yl*2080 + c*130;
    float v0=slab[sb+l], v1=slab[sb+64+l];
    int r0=rev7(l), r1=rev7(64+l);
    Ar[wb+r0]=v0; Ai[wb+r0]=0.f;
    Ar[wb+r1]=v1; Ai[wb+r1]=0.f;
    fft128(Ar+wb, Ai+wb, ct, st, l, -1.f);
    int ob = yl*1056 + c*66;
    outre[ob+l]=Ar[wb+l]; outim[ob+l]=Ai[wb+l];
    if(l==0){ outre[ob+64]=Ar[wb+64]; outim[ob+64]=Ai[wb+64]; }
  }
  __syncthreads();
  long obase = ((long)(b*128+y0))*1040;
  for(int e=t;e<2080;e+=256){
    int yl=e/1040, rem=e%1040, v=rem>>4, c=rem&15;
    Rre[obase+e]=outre[yl*1056 + c*66 + v];
    Rim[obase+e]=outim[yl*1056 + c*66 + v];
  }
}

// F2+F3: col fft over y (ortho 1/128), amp/phase, masked channel-mix + gelu.
// grid 4b*65v, 256thr. R[b][y][v][c] -> glo/ghi/pho [b][u][v][c]
__global__ void k_fft_col(const float* Rre, const float* Rim,
                          float* glo, float* ghi, float* pho,
                          const void* alpw, const void* ahpw,
                          const void* phpw, const void* phs, const int* flg){
  __shared__ float sre[2080], sim[2080];  // [16c][130]  (in: y, out: amp/ph over u)
  __shared__ float og[2080], oh[2080], op[2080];
  __shared__ float Ar[512], Ai[512];
  __shared__ float ct[128], st[128];
  __shared__ float wl[256], wh[256], wp[256];
  int t=threadIdx.x;
  int bf=*flg;
  int b = blockIdx.x/65, v = blockIdx.x%65;
  MAKE_TW(ct,st);
  wl[t]=LD(alpw,t,bf); wh[t]=LD(ahpw,t,bf); wp[t]=LD(phpw,t,bf);
  long ibase = ((long)b*128)*1040 + v*16;
  for(int e=t;e<2048;e+=256){
    int y=e>>4, c=e&15;
    sre[c*130+y]=Rre[ibase + (long)y*1040 + c];
    sim[c*130+y]=Rim[ibase + (long)y*1040 + c];
  }
  __syncthreads();
  int w=t>>6, l=t&63, wb=w<<7;
  const float inv=1.f/128.f;
  for(int c=w; c<16; c+=4){
    int sb=c*130;
    float x0r=sre[sb+l], x0i=sim[sb+l], x1r=sre[sb+64+l], x1i=sim[sb+64+l];
    int r0=rev7(l), r1=rev7(64+l);
    Ar[wb+r0]=x0r; Ai[wb+r0]=x0i;
    Ar[wb+r1]=x1r; Ai[wb+r1]=x1i;
    fft128(Ar+wb, Ai+wb, ct, st, l, -1.f);
    float re0=Ar[wb+l]*inv, im0=Ai[wb+l]*inv;
    float re1=Ar[wb+64+l]*inv, im1=Ai[wb+64+l]*inv;
    sre[sb+l]=sqrtf(re0*re0+im0*im0); sim[sb+l]=atan2f(im0,re0);
    sre[sb+64+l]=sqrtf(re1*re1+im1*im1); sim[sb+64+l]=atan2f(im1,re1);
  }
  __syncthreads();
  // F3 mix at (u,v): needs all 16 channels (in LDS)
  {
    int u = t&127, half = t>>7;
    float yy=(float)u/127.f, xx=(float)v/64.f;
    float rr=sqrtf(yy*yy+xx*xx);
    float lo = 1.f/(1.f+expf((rr-0.25f)*20.f));
    float hi = 1.f-lo;
    float av[16], pv[16];
    for(int ch=0;ch<16;ch++){ av[ch]=sre[ch*130+u]; pv[ch]=sim[ch*130+u]; }
    float pscale = LD(phs,0,bf);
    for(int c=half*8;c<half*8+8;c++){
      float al=0.f, ah=0.f, pp=0.f;
      for(int ch=0;ch<16;ch++){
        float a=av[ch];
        al += wl[c*16+ch]*(a*lo);
        ah += wh[c*16+ch]*(a*hi);
        pp += wp[c*16+ch]*pv[ch];
      }
      og[c*130+u]=geluf(al); oh[c*130+u]=geluf(ah); op[c*130+u]=pv[c]+pscale*pp;
    }
  }
  __syncthreads();
  long obase = ((long)b*128)*1040 + v*16;
  for(int e=t;e<2048;e+=256){
    int u=e>>4, c=e&15;
    long o = obase + (long)u*1040 + c;
    glo[o]=og[c*130+u]; ghi[o]=oh[c*130+u]; pho[o]=op[c*130+u];
  }
}

// F4: depthwise 3x3 over (u,v) on lo/hi + Y = amp*e^{i phase}. channel-last, coalesced.
__global__ void k_four_dw(const float* glo, const float* ghi, const float* pho,
                          float* Yre, float* Yim,
                          const void* aldw, const void* ahdw, const int* flg){
  int bf=*flg;
  __shared__ float wl[144], wh[144];
  int t=threadIdx.x;
  if(t<144){wl[t]=LD(aldw,t,bf); wh[t]=LD(ahdw,t,bf);}
  __syncthreads();
  long o = (long)blockIdx.x*256+t;  // 532480 exact
  int c=(int)(o&15); long r=o>>4; int v=(int)(r%65); long r2=r/65; int u=(int)(r2&127); int b=(int)(r2>>7);
  float acc=0.f;
  for(int dp=0;dp<3;dp++){
    int uu=u-1+dp; if(uu<0||uu>=128) continue;
    for(int dq=0;dq<3;dq++){
      int vv=v-1+dq; if(vv<0||vv>=65) continue;
      long idx=(((long)(b*128+uu))*65+vv)*16+c;
      acc += wl[c*9+dp*3+dq]*glo[idx] + wh[c*9+dp*3+dq]*ghi[idx];
    }
  }
  float pvv = pho[o];
  float s_,c_; sincosf(pvv,&s_,&c_);
  Yre[o]=acc*c_; Yim[o]=acc*s_;
}

// I1: inverse col fft over u (e^{+i}, unscaled). grid 4b*65, Y[b][u][v][c] -> Z[b][y][v][c]
__global__ void k_ifft_col(const float* Yre, const float* Yim, float* Zre, float* Zim){
  __shared__ float sre[2080], sim[2080];  // [16c][130]
  __shared__ float Ar[512], Ai[512];
  __shared__ float ct[128], st[128];
  int t=threadIdx.x;
  int b = blockIdx.x/65, v = blockIdx.x%65;
  MAKE_TW(ct,st);
  long ibase = ((long)b*128)*1040 + v*16;
  for(int e=t;e<2048;e+=256){
    int u=e>>4, c=e&15;
    sre[c*130+u]=Yre[ibase + (long)u*1040 + c];
    sim[c*130+u]=Yim[ibase + (long)u*1040 + c];
  }
  __syncthreads();
  int w=t>>6, l=t&63, wb=w<<7;
  for(int c=w; c<16; c+=4){
    int sb=c*130;
    float x0r=sre[sb+l], x0i=sim[sb+l], x1r=sre[sb+64+l], x1i=sim[sb+64+l];
    int r0=rev7(l), r1=rev7(64+l);
    Ar[wb+r0]=x0r; Ai[wb+r0]=x0i;
    Ar[wb+r1]=x1r; Ai[wb+r1]=x1i;
    fft128(Ar+wb, Ai+wb, ct, st, l, +1.f);
    sre[sb+l]=Ar[wb+l]; sim[sb+l]=Ai[wb+l];
    sre[sb+64+l]=Ar[wb+64+l]; sim[sb+64+l]=Ai[wb+64+l];
  }
  __syncthreads();
  long obase = ibase;
  for(int e=t;e<2048;e+=256){
    int y=e>>4, c=e&15;
    Zre[obase + (long)y*1040 + c]=sre[c*130+y];
    Zim[obase + (long)y*1040 + c]=sim[c*130+y];
  }
}

// I2: hermitian irfft over v (65->128), scale 1/128. grid 4b*64yg.
// Z[b][y][v][c] -> km NHWC
__global__ void k_ifft_row(const float* Zre, const float* Zim, float* km){
  __shared__ float szre[2112], szim[2112];  // [2y][16c][66]
  __shared__ float oslab[4160];             // [2y][16c][130]
  __shared__ float Ar[512], Ai[512];
  __shared__ float ct[128], st[128];
  int t=threadIdx.x;
  int b = blockIdx.x>>6, y0 = (blockIdx.x&63)<<1;
  MAKE_TW(ct,st);
  long ibase = ((long)(b*128+y0))*1040;
  for(int e=t;e<2080;e+=256){
    int yl=e/1040, rem=e%1040, v=rem>>4, c=rem&15;
    szre[yl*1056 + c*66 + v]=Zre[ibase+e];
    szim[yl*1056 + c*66 + v]=Zim[ibase+e];
  }
  __syncthreads();
  int w=t>>6, l=t&63, wb=w<<7;
  const float inv=1.f/128.f;
  for(int li=w; li<32; li+=4){
    int yl=li>>4, c=li&15;
    int sb = yl*1056 + c*66;
    // build hermitian spectrum S[128]: S[0]=(re0,0), S[64]=(re64,0), S[128-k]=conj(S[k])
    float zr0 = szre[sb+l];
    float zi0 = (l==0)?0.f:szim[sb+l];
    float zr1, zi1;
    if(l==0){ zr1=szre[sb+64]; zi1=0.f; }
    else    { zr1=szre[sb+64-l]; zi1=-szim[sb+64-l]; }
    int r0=rev7(l), r1=rev7(64+l);
    Ar[wb+r0]=zr0; Ai[wb+r0]=zi0;
    Ar[wb+r1]=zr1; Ai[wb+r1]=zi1;
    fft128(Ar+wb, Ai+wb, ct, st, l, +1.f);
    int ob = yl*2080 + c*130;
    oslab[ob+l]=Ar[wb+l]*inv;
    oslab[ob+64+l]=Ar[wb+64+l]*inv;
  }
  __syncthreads();
  long obase = ((long)(b*128+y0))*2048;
  for(int e=t;e<4096;e+=256){
    int yl=e>>11, rem=e&2047, x=rem>>4, c=rem&15;
    km[obase+e]=oslab[yl*2080 + c*130 + x];
  }
}

// W_A: fused haar + BN + mlp_in (48->96), channels-last m96 [b][4096][96]
__global__ void k_wave_a(const float* vd, float* m96, const void* win,
                         const void* bng, const void* bnb, const int* flg){
  int bf=*flg;
  __shared__ float wi[4608];   // transposed [cc][96ch]
  __shared__ float vds[1024];
  __shared__ float ns[768];
  __shared__ float gs[48], bs[48];
  int t=threadIdx.x; // 192
  int b = blockIdx.x>>8;
  int ij0 = (blockIdx.x&255)<<4;
  for(int i=t;i<4608;i+=192){ int cc=i/96, ch=i%96; wi[cc*96+ch]=LD(win,(long)ch*48+cc,bf); }
  if(t<48){ gs[t]=LD(bng,t,bf)*(1.f/sqrtf(1.f+1e-5f)); bs[t]=LD(bnb,t,bf); }
  int i0 = ij0>>6, j0 = ij0&63;
  long rb0 = ((long)(b*128 + 2*i0)*128 + 2*j0)*16;
  for(int i=t;i<512;i+=192){ vds[i]=vd[rb0+i]; vds[512+i]=vd[rb0+2048+i]; }
  __syncthreads();
  for(int o=t;o<768;o+=192){
    int p=o/48, cc2=o%48;
    int m=cc2+16, c=m>>2, f=m&3;
    float a =vds[(2*p)*16+c],     bv=vds[(2*p+1)*16+c];
    float cv=vds[512+(2*p)*16+c], dv=vds[512+(2*p+1)*16+c];
    float v;
    if(f==0)      v=(a+bv+cv+dv);
    else if(f==1) v=(a-bv+cv-dv);
    else if(f==2) v=(a+bv-cv-dv);
    else          v=(a-bv-cv+dv);
    ns[o] = v*0.5f*gs[cc2]+bs[cc2];
  }
  __syncthreads();
  long ob = ((long)b*4096 + ij0)*96;
  for(int o=t;o<1536;o+=192){
    int p=o/96, ch=o%96;
    float acc=0.f;
    for(int cc=0;cc<48;cc++) acc += wi[cc*96+ch]*ns[p*48+cc];
    m96[ob+o]=acc;
  }
}

// W_DW: depthwise 3x3 + gelu, channels-last coalesced; grid 6144x256
__global__ void k_wave_dw(const float* m96, float* g96, const void* wdw_, const int* flg){
  int bf=*flg;
  __shared__ float wdw[864];
  int t=threadIdx.x;
  for(int i=t;i<864;i+=256) wdw[i]=LD(wdw_,i,bf);
  __syncthreads();
  int o = blockIdx.x*256+t;   // 1,572,864 exact
  int ch = o%96; int r = o/96; int px = r&4095; int b = r>>12;
  int i = px>>6, j = px&63;
  long mb = (long)b*393216;
  float acc=0.f;
  for(int dp=0;dp<3;dp++){ int ii=i-1+dp; if(ii<0||ii>=64) continue;
    for(int dq=0;dq<3;dq++){ int jj=j-1+dq; if(jj<0||jj>=64) continue;
      acc += wdw[ch*9+dp*3+dq]*m96[mb + (long)(ii*64+jj)*96 + ch]; } }
  g96[o]=geluf(acc);
}

// A1: per-batch Gram matrices
__global__ void k_gram(const float* qm, const float* km, float* G){
  __shared__ float qs[256*16], ks[256*16];
  int b=blockIdx.x>>5; int chunk=blockIdx.x&31;
  int t=threadIdx.x; int r=t>>4, s=t&15;
  float akq=0.f, akk=0.f, aqq=0.f;
  for(int tile=0;tile<2;tile++){
    long pb=((long)b*HW + chunk*512 + tile*256)*16;
    for(int i=t;i<4096;i+=256){ qs[i]=qm[pb+i]; ks[i]=km[pb+i]; }
    __syncthreads();
    for(int p=0;p<256;p++){
      float kv=ks[p*16+r], qv=qs[p*16+s];
      akq += kv*qv;
      akk += kv*ks[p*16+s];
      aqq += qs[p*16+r]*qv;
    }
    __syncthreads();
  }
  float* Gb=G + b*768;
  atomicAdd(&Gb[t], akq);
  atomicAdd(&Gb[256+t], akk);
  atomicAdd(&Gb[512+t], aqq);
}

// A2: per (b,h): attn from Gram -> fold into M_b[16,64]
__global__ void k_attn(const float* G, float* Mb, const void* We,
                       const void* Wproj, const void* resc, const int* flg){
  int bf=*flg;
  __shared__ float wes[16*64];
  __shared__ float gkq[256], gkk[256], gqq[256];
  __shared__ float ukq[64*16], ukk[64*16], uqq[64*16];
  __shared__ float nk[64], nq[64];
  __shared__ float A[64*64];
  __shared__ float T[64*16];
  __shared__ float wpj[64*64];
  int b=blockIdx.x>>3, h=blockIdx.x&7;
  int t=threadIdx.x;
  for(int i=t;i<1024;i+=256){ int rr=i>>6, e=i&63; wes[rr*64+e]=LD(We, (long)rr*512 + h*64 + e, bf); }
  gkq[t]=G[b*768+t]; gkk[t]=G[b*768+256+t]; gqq[t]=G[b*768+512+t];
  for(int i=t;i<4096;i+=256){ int d=i>>6, c=i&63; wpj[i]=LD(Wproj,(long)(h*64+d)*64+c,bf); }
  __syncthreads();
  for(int i=t;i<1024;i+=256){
    int d=i>>4, s=i&15;
    float a1=0.f,a2=0.f,a3=0.f;
    for(int rr=0;rr<16;rr++){ float wv=wes[rr*64+d]; a1+=wv*gkq[rr*16+s]; a2+=wv*gkk[rr*16+s]; a3+=wv*gqq[rr*16+s]; }
    ukq[i]=a1; ukk[i]=a2; uqq[i]=a3;
  }
  __syncthreads();
  if(t<64){ float a=0.f; for(int s=0;s<16;s++) a+=ukk[t*16+s]*wes[s*64+t]; nk[t]=fmaxf(sqrtf(a),1e-12f); }
  else if(t<128){ int e=t-64; float a=0.f; for(int s=0;s<16;s++) a+=uqq[e*16+s]*wes[s*64+e]; nq[e]=fmaxf(sqrtf(a),1e-12f); }
  __syncthreads();
  float rsc=LD(resc,h,bf);
  for(int i=t;i<4096;i+=256){
    int d=i>>6, e=i&63;
    float a=0.f; for(int s=0;s<16;s++) a+=ukq[d*16+s]*wes[s*64+e];
    A[i]=a/(nk[d]*nq[e])*rsc;
  }
  __syncthreads();
  if(t<64){
    int d=t; float m=-1e30f;
    for(int e=0;e<64;e++) m=fmaxf(m,A[d*64+e]);
    float sum=0.f;
    for(int e=0;e<64;e++){ float ev=expf(A[d*64+e]-m); A[d*64+e]=ev; sum+=ev; }
    float inv=1.f/sum;
    for(int e=0;e<64;e++) A[d*64+e]*=inv;
  }
  __syncthreads();
  for(int i=t;i<1024;i+=256){
    int d=i>>4, s=i&15;
    float a=0.f; for(int e=0;e<64;e++) a+=A[d*64+e]*wes[s*64+e];
    T[i]=a;
  }
  __syncthreads();
  for(int i=t;i<1024;i+=256){
    int s=i>>6, c=i&63;
    float a=0.f; for(int d=0;d<64;d++) a+=T[d*16+s]*wpj[d*64+c];
    atomicAdd(&Mb[b*1024 + s*64 + c], a);
  }
}

// W_EPI: mlp_out(96->48) + residual haar + IWT + (vm row)@M_b + bproj -> d_out
// grid 4b*64 tiles (8x8 half-px = 16x16 out px), 256 thr
__global__ void k_wave_epi(const float* g96, const float* vd, const float* Mb_,
                           const void* wout_, const void* rs_, const void* bproj,
                           void* out, const int* flg){
  int bf=*flg;
  __shared__ float wt[4608];   // [96ch][48cc]
  __shared__ float gt[6144];   // [64 px][96]
  __shared__ float he[4096];   // [64 px][4 pos][16 ch]
  __shared__ float mb[1024];   // [16 s][64 c]
  __shared__ float bias[64];
  int t=threadIdx.x; // 256
  int b=blockIdx.x>>6; int tile=blockIdx.x&63;
  int i0=(tile>>3)<<3, j0=(tile&7)<<3;
  for(int i=t;i<4608;i+=256){ int ch=i/48, cc=i%48; wt[ch*48+cc]=LD(wout_,(long)cc*96+ch,bf); }
  for(int i=t;i<6144;i+=256){
    int px=i/96, ch=i%96;
    int gi=i0+(px>>3), gj=j0+(px&7);
    gt[i]=g96[((long)b*4096 + gi*64+gj)*96 + ch];
  }
  for(int i=t;i<1024;i+=256) mb[i]=Mb_[b*1024+i];
  if(t<64) bias[t]=LD(bproj,t,bf);
  __syncthreads();
  float rs=LD(rs_,0,bf);
  for(int o=t;o<3072;o+=256){
    int px=o/48, cc=o%48;
    int gi=i0+(px>>3), gj=j0+(px&7);
    float acc=0.f;
    for(int ch=0;ch<96;ch++) acc += wt[ch*48+cc]*gt[px*96+ch];
    long vb = ((long)(b*128+2*gi)*128 + 2*gj)*16;
    int m=cc+16, c=m>>2, f=m&3;
    float a=vd[vb+c], bv=vd[vb+16+c], cv=vd[vb+2048+c], dv=vd[vb+2048+16+c];
    float hv;
    if(f==0)      hv=(a+bv+cv+dv);
    else if(f==1) hv=(a-bv+cv-dv);
    else if(f==2) hv=(a+bv-cv-dv);
    else          hv=(a-bv-cv+dv);
    he[px*64 + 16 + cc] = hv*0.5f + rs*acc;
  }
  for(int o=t;o<1024;o+=256){
    int px=o>>4, c16=o&15;
    int gi=i0+(px>>3), gj=j0+(px&7);
    long vb=((long)(b*128+2*gi)*128+2*gj)*16;
    int c=c16>>2, f=c16&3;
    float a=vd[vb+c], bv=vd[vb+16+c], cv=vd[vb+2048+c], dv=vd[vb+2048+16+c];
    float hv;
    if(f==0)      hv=(a+bv+cv+dv);
    else if(f==1) hv=(a-bv+cv-dv);
    else if(f==2) hv=(a+bv-cv-dv);
    else          hv=(a-bv-cv+dv);
    he[px*64+c16]=hv*0.5f;
  }
  __syncthreads();
  // epilogue GEMM: out px row = he[halfpx][pos][0..15] @ mb + bias, coalesced 256B stores
  for(int ok=t; ok<16384; ok+=256){
    int c=ok&63, px=ok>>6;
    int orow=px>>4, ocol=px&15;
    int halfpx=(orow>>1)*8 + (ocol>>1);
    int pos=((orow&1)<<1)|(ocol&1);
    const float* hv = he + halfpx*64 + pos*16;
    float acc=bias[c];
    for(int s=0;s<16;s++) acc += hv[s]*mb[s*64+c];
    long oo = (((long)(b*128 + 2*i0+orow))*128 + (2*j0+ocol))*64 + c;
    if(bf) ((__hip_bfloat16*)out)[oo]=__float2bfloat16(acc);
    else   ((float*)out)[oo]=acc;
  }
}

extern "C" void kernel_launch(void* const* d_in, const int* in_sizes, int n_in,
                              void* d_out, int out_size, void* d_ws, size_t ws_size,
                              hipStream_t stream) {
  const void* x_in   = d_in[0];
  const void* Wq     = d_in[1];
  const void* Wk     = d_in[2];
  const void* Wv     = d_in[3];
  const void* Wr     = d_in[4];
  const void* We     = d_in[5];
  const void* qs_dw  = d_in[6];
  const void* qs_pw  = d_in[7];
  const void* qs_g   = d_in[8];
  const void* al_pw  = d_in[9];
  const void* al_dw  = d_in[10];
  const void* ah_pw  = d_in[11];
  const void* ah_dw  = d_in[12];
  const void* ph_pw  = d_in[13];
  const void* ph_s   = d_in[14];
  const void* bn_g   = d_in[15];
  const void* bn_b   = d_in[16];
  const void* mlp_in = d_in[17];
  const void* mlp_dw = d_in[18];
  const void* mlp_out= d_in[19];
  const void* res_s  = d_in[20];
  const void* rescale= d_in[21];
  const void* Wproj  = d_in[22];
  const void* bproj  = d_in[23];
  float* ws = (float*)d_ws;
  const int* flg = ((const int*)ws) + OFF_FLAG;

  float* FA = ws + OFF_S;
  float* FB = FA + FSZ;
  float* FC = FB + FSZ;
  float* FD = FC + FSZ;
  float* FE = FD + FSZ;
  float* M96 = ws + OFF_VMIX;            // reuse freed vmix + beyond? no: use OFF_VMIX (1M) for m96 (1.5M) -> keep at OFF_S? FFT bufs live. Use dedicated:
  M96 = FE + FSZ;                        // after FFT buffers
  float* G96 = M96 + 1572864;

  k_flag<<<1,256,0,stream>>>(bn_g, ws);
  k_fold<<<3,256,0,stream>>>(Wq,Wk,Wv,Wr, ws, flg);
  k_dims<<<4096,256,0,stream>>>(x_in, ws, ws+OFF_QDIM, ws+OFF_KDIM, ws+OFF_VDIM, flg);
  k_spatial<<<512,128,0,stream>>>(ws+OFF_QDIM, ws+OFF_QMIX, qs_dw, qs_pw, qs_g, flg);
  // Fourier branch (k): radix-2, channel-last, contiguous stores
  k_fft_row<<<256,256,0,stream>>>(ws+OFF_KDIM, FA, FB);
  k_fft_col<<<260,256,0,stream>>>(FA, FB, FC, FD, FE, al_pw, ah_pw, ph_pw, ph_s, flg);
  k_four_dw<<<2080,256,0,stream>>>(FC, FD, FE, FA, FB, al_dw, ah_dw, flg);
  k_ifft_col<<<260,256,0,stream>>>(FA, FB, FC, FD);
  k_ifft_row<<<256,256,0,stream>>>(FC, FD, ws+OFF_KMIX);
  // Attention (Gram-collapsed) — before wavelet tail so M_b is ready for the epilogue
  k_gram<<<128,256,0,stream>>>(ws+OFF_QMIX, ws+OFF_KMIX, ws+OFF_G);
  k_attn<<<32,256,0,stream>>>(ws+OFF_G, ws+OFF_MB, We, Wproj, rescale, flg);
  // Wavelet branch (v) + fused epilogue -> d_out
  k_wave_a<<<1024,192,0,stream>>>(ws+OFF_VDIM, M96, mlp_in, bn_g, bn_b, flg);
  k_wave_dw<<<6144,256,0,stream>>>(M96, G96, mlp_dw, flg);
  k_wave_epi<<<256,256,0,stream>>>(G96, ws+OFF_VDIM, ws+OFF_MB, mlp_out, res_s, bproj, d_out, flg);
}

// Round 6
// 388.997 us; speedup vs baseline: 2.6149x; 1.2818x over previous
//
#include <hip/hip_runtime.h>
#include <hip/hip_bf16.h>
#include <math.h>

#define HW 16384

__device__ __forceinline__ float LD(const void* p, long i, int bf){
  return bf ? __bfloat162float(((const __hip_bfloat16*)p)[i]) : ((const float*)p)[i];
}
__device__ __forceinline__ float geluf(float x){ return 0.5f*x*(1.0f + erff(x*0.70710678118654752f)); }
__device__ __forceinline__ int rev7(int i){ return (int)(__brev((unsigned)i)>>25); }

__device__ __forceinline__ void fft128(float* Ar, float* Ai, const float* ct, const float* st,
                                       int lane, float dir){
  #pragma unroll
  for(int len=2; len<=128; len<<=1){
    int half=len>>1;
    int pos = lane & (half-1);
    int i1 = ((lane & ~(half-1))<<1) | pos;
    int i2 = i1 + half;
    int tw = pos * (128/len);
    float wr = ct[tw], wi = dir*st[tw];
    float xr=Ar[i2], xi=Ai[i2];
    float tr = xr*wr - xi*wi;
    float ti = xr*wi + xi*wr;
    float ur=Ar[i1], ui=Ai[i1];
    Ar[i1]=ur+tr; Ai[i1]=ui+ti;
    Ar[i2]=ur-tr; Ai[i2]=ui-ti;
  }
}

#define MAKE_TWP(ct,st) { int tt=threadIdx.x; if(tt<128){ float ang=6.283185307179586f*(float)tt/128.f; float s_,c_; sincosf(ang,&s_,&c_); (ct)[tt]=c_; (st)[tt]=s_; } }

// ---- ws layout (float offsets) ----
#define OFF_M    0
#define OFF_G    3072
#define OFF_MB   6144
#define OFF_FLAG 10240
#define OFF_QDIM 16384
#define OFF_KDIM (16384 + 1048576)
#define OFF_VDIM (16384 + 2*1048576)
#define OFF_QMIX (16384 + 3*1048576)
#define OFF_KMIX (16384 + 4*1048576)
#define OFF_S    (16384 + 5*1048576)
#define FSZ 532480            // 4*128*65*16
// FA..FE = OFF_S..+5*FSZ ; M96 = FE+FSZ (1.5M) ; G96 overlays dead qd/kd @OFF_QDIM

// K0: fold (48 blocks) + flag/zero (block 48)
__global__ void k_head(const void* Wq, const void* Wk, const void* Wv,
                       const void* Wr, const void* bng, float* ws){
  __shared__ float wr[8192];
  __shared__ float part[256];
  int blk=blockIdx.x, t=threadIdx.x;
  if(blk==48){
    for(int i=3072+t;i<10240;i+=256) ws[i]=0.f;
    if(t==0){
      float v = ((const float*)bng)[0];
      ((int*)ws)[OFF_FLAG] = (v==1.0f) ? 0 : 1;
    }
    return;
  }
  int bf = (((const float*)bng)[0]==1.0f) ? 0 : 1;
  int mat=blk>>4, seg=blk&15;
  const void* Wsrc = mat==0 ? Wq : (mat==1 ? Wk : Wv);
  for(int i=t;i<8192;i+=256) wr[i]=LD(Wr,i,bf);
  __syncthreads();
  int o=t&63, jseg=t>>6;
  int c=seg*4+(o>>4), r=o&15;
  float acc=0.f;
  for(int j=jseg*128;j<jseg*128+128;j++) acc += LD(Wsrc,(long)c*512+j,bf)*wr[j*16+r];
  part[jseg*64+o]=acc;
  __syncthreads();
  if(t<64){
    float s=part[t]+part[64+t]+part[128+t]+part[192+t];
    int cc=seg*4+(t>>4), rr=t&15;
    ws[mat*1024 + cc*16 + rr]=s;
  }
}

// K1: q/k/v_dim = x @ M{q,k,v}
__global__ void k_dims(const void* x, const float* ws,
                       float* qd, float* kd, float* vd, const int* flg){
  int bf=*flg;
  __shared__ float xs[16*64];
  __shared__ float ms[3*1024];
  int b = blockIdx.x>>10;
  int pix0 = (blockIdx.x & 1023)<<4;
  int t = threadIdx.x;
  for(int i=t;i<3072;i+=256) ms[i]=ws[i];
  long base = ((long)b*HW + pix0)*64;
  for(int i=t;i<1024;i+=256) xs[i]=LD(x, base+i, bf);
  __syncthreads();
  int p=t>>4, r=t&15;
  float aq=0.f,ak=0.f,av=0.f;
  for(int c=0;c<64;c++){
    float xv = xs[p*64+c];
    aq += xv*ms[c*16+r];
    ak += xv*ms[1024+c*16+r];
    av += xv*ms[2048+c*16+r];
  }
  long o = ((long)b*HW + pix0)*16 + t;
  qd[o]=aq; kd[o]=ak; vd[o]=av;
}

// K2 merged: [0,256) spatial (2 rows/blk) | [256,512) fft_row | [512,1536) wave_a
__global__ void k_mix3(const float* qd, float* qm, const void* dw, const void* pw, const void* gamma,
                       const float* kd, float* Rre, float* Rim,
                       const float* vd, float* m96, const void* win, const void* bng, const void* bnb,
                       const int* flg){
  __shared__ float smem[9664];
  int bf=*flg;
  int blk=blockIdx.x, t=threadIdx.x;
  if(blk<256){
    // ---- SpitialUnit, 2 y-rows per block ----
    float* tile=smem; float* dws=smem+8704; float* pws=smem+8848; float* gsm=smem+9104;
    int b=blk>>6, y0=(blk&63)<<1;
    for(int i=t;i<144;i+=256) dws[i]=LD(dw,i,bf);
    if(t<256) pws[t]=LD(pw,t,bf);
    if(t<16) gsm[t]=LD(gamma,t,bf);
    for(int i=t;i<8192;i+=256){
      int ry=i>>11, rem=i&2047, xx=rem>>4, ch=rem&15;
      int yy=y0-1+ry;
      tile[(ry*128+xx)*17+ch] = (yy>=0&&yy<128) ? qd[(long)(b*128+yy)*2048 + rem] : 0.f;
    }
    __syncthreads();
    int ty=t>>7, x=t&127;
    float g[16];
    for(int ch=0;ch<16;ch++){
      float acc=0.f;
      for(int p=0;p<3;p++)
        for(int q=0;q<3;q++){
          int xx=x-1+q;
          if(xx>=0&&xx<128) acc += dws[ch*9+p*3+q]*tile[((ty+p)*128+xx)*17+ch];
        }
      g[ch]=geluf(acc);
    }
    long ob = ((long)(b*128+y0+ty)*128 + x)*16;
    for(int c=0;c<16;c++){
      float acc=0.f;
      for(int ch=0;ch<16;ch++) acc += pws[c*16+ch]*g[ch];
      qm[ob+c] = tile[((1+ty)*128+x)*17+c] + gsm[c]*acc;
    }
  } else if(blk<512){
    // ---- row rfft: kd NHWC -> R[b][y][v][c] ----
    float* slab=smem; float* outre=smem+4160; float* outim=smem+6272;
    float* Ar=smem+8384; float* Ai=smem+8896; float* ct=smem+9408; float* st=smem+9536;
    int blk2=blk-256;
    int b=blk2>>6, y0=(blk2&63)<<1;
    MAKE_TWP(ct,st);
    long gbase = ((long)(b*128+y0))*2048;
    for(int e=t;e<4096;e+=256){
      int yl=e>>11, rem=e&2047, x=rem>>4, c=rem&15;
      slab[yl*2080 + c*130 + x] = kd[gbase + e];
    }
    __syncthreads();
    int w=t>>6, l=t&63, wb=w<<7;
    for(int li=w; li<32; li+=4){
      int yl=li>>4, c=li&15;
      int sb = yl*2080 + c*130;
      float v0=slab[sb+l], v1=slab[sb+64+l];
      int r0=rev7(l), r1=rev7(64+l);
      Ar[wb+r0]=v0; Ai[wb+r0]=0.f;
      Ar[wb+r1]=v1; Ai[wb+r1]=0.f;
      fft128(Ar+wb, Ai+wb, ct, st, l, -1.f);
      int ob = yl*1056 + c*66;
      outre[ob+l]=Ar[wb+l]; outim[ob+l]=Ai[wb+l];
      if(l==0){ outre[ob+64]=Ar[wb+64]; outim[ob+64]=Ai[wb+64]; }
    }
    __syncthreads();
    long obase = ((long)(b*128+y0))*1040;
    for(int e=t;e<2080;e+=256){
      int yl=e/1040, rem=e%1040, v=rem>>4, c=rem&15;
      Rre[obase+e]=outre[yl*1056 + c*66 + v];
      Rim[obase+e]=outim[yl*1056 + c*66 + v];
    }
  } else {
    // ---- wave_a: haar + BN + mlp_in (48->96) -> m96 [b][4096][96] ----
    float* wi=smem; float* vds=smem+4608; float* ns=smem+5632;
    float* gsm=smem+6400; float* bsm=smem+6448;
    int blk3=blk-512;
    int b = blk3>>8;
    int ij0 = (blk3&255)<<4;
    for(int i=t;i<4608;i+=256){ int cc=i/96, ch=i%96; wi[cc*96+ch]=LD(win,(long)ch*48+cc,bf); }
    if(t<48){ gsm[t]=LD(bng,t,bf)*(1.f/sqrtf(1.f+1e-5f)); bsm[t]=LD(bnb,t,bf); }
    int i0 = ij0>>6, j0 = ij0&63;
    long rb0 = ((long)(b*128 + 2*i0)*128 + 2*j0)*16;
    for(int i=t;i<512;i+=256){ vds[i]=vd[rb0+i]; vds[512+i]=vd[rb0+2048+i]; }
    __syncthreads();
    for(int o=t;o<768;o+=256){
      int p=o/48, cc2=o%48;
      int m=cc2+16, c=m>>2, f=m&3;
      float a =vds[(2*p)*16+c],     bv=vds[(2*p+1)*16+c];
      float cv=vds[512+(2*p)*16+c], dv=vds[512+(2*p+1)*16+c];
      float v;
      if(f==0)      v=(a+bv+cv+dv);
      else if(f==1) v=(a-bv+cv-dv);
      else if(f==2) v=(a+bv-cv-dv);
      else          v=(a-bv-cv+dv);
      ns[o] = v*0.5f*gsm[cc2]+bsm[cc2];
    }
    __syncthreads();
    long ob = ((long)b*4096 + ij0)*96;
    for(int o=t;o<1536;o+=256){
      int p=o/96, ch=o%96;
      float acc=0.f;
      for(int cc=0;cc<48;cc++) acc += wi[cc*96+ch]*ns[p*48+cc];
      m96[ob+o]=acc;
    }
  }
}

// F2+F3: col fft over y (ortho), amp/phase, masked channel-mix + gelu
__global__ void k_fft_col(const float* Rre, const float* Rim,
                          float* glo, float* ghi, float* pho,
                          const void* alpw, const void* ahpw,
                          const void* phpw, const void* phs, const int* flg){
  __shared__ float sre[2080], sim[2080];
  __shared__ float og[2080], oh[2080], op[2080];
  __shared__ float Ar[512], Ai[512];
  __shared__ float ct[128], st[128];
  __shared__ float wl[256], wh[256], wp[256];
  int t=threadIdx.x;
  int bf=*flg;
  int b = blockIdx.x/65, v = blockIdx.x%65;
  MAKE_TWP(ct,st);
  wl[t]=LD(alpw,t,bf); wh[t]=LD(ahpw,t,bf); wp[t]=LD(phpw,t,bf);
  long ibase = ((long)b*128)*1040 + v*16;
  for(int e=t;e<2048;e+=256){
    int y=e>>4, c=e&15;
    sre[c*130+y]=Rre[ibase + (long)y*1040 + c];
    sim[c*130+y]=Rim[ibase + (long)y*1040 + c];
  }
  __syncthreads();
  int w=t>>6, l=t&63, wb=w<<7;
  const float inv=1.f/128.f;
  for(int c=w; c<16; c+=4){
    int sb=c*130;
    float x0r=sre[sb+l], x0i=sim[sb+l], x1r=sre[sb+64+l], x1i=sim[sb+64+l];
    int r0=rev7(l), r1=rev7(64+l);
    Ar[wb+r0]=x0r; Ai[wb+r0]=x0i;
    Ar[wb+r1]=x1r; Ai[wb+r1]=x1i;
    fft128(Ar+wb, Ai+wb, ct, st, l, -1.f);
    float re0=Ar[wb+l]*inv, im0=Ai[wb+l]*inv;
    float re1=Ar[wb+64+l]*inv, im1=Ai[wb+64+l]*inv;
    sre[sb+l]=sqrtf(re0*re0+im0*im0); sim[sb+l]=atan2f(im0,re0);
    sre[sb+64+l]=sqrtf(re1*re1+im1*im1); sim[sb+64+l]=atan2f(im1,re1);
  }
  __syncthreads();
  {
    int u = t&127, half = t>>7;
    float yy=(float)u/127.f, xx=(float)v/64.f;
    float rr=sqrtf(yy*yy+xx*xx);
    float lo = 1.f/(1.f+expf((rr-0.25f)*20.f));
    float hi = 1.f-lo;
    float av[16], pv[16];
    for(int ch=0;ch<16;ch++){ av[ch]=sre[ch*130+u]; pv[ch]=sim[ch*130+u]; }
    float pscale = LD(phs,0,bf);
    for(int c=half*8;c<half*8+8;c++){
      float al=0.f, ah=0.f, pp=0.f;
      for(int ch=0;ch<16;ch++){
        float a=av[ch];
        al += wl[c*16+ch]*(a*lo);
        ah += wh[c*16+ch]*(a*hi);
        pp += wp[c*16+ch]*pv[ch];
      }
      og[c*130+u]=geluf(al); oh[c*130+u]=geluf(ah); op[c*130+u]=pv[c]+pscale*pp;
    }
  }
  __syncthreads();
  long obase = ((long)b*128)*1040 + v*16;
  for(int e=t;e<2048;e+=256){
    int u=e>>4, c=e&15;
    long o = obase + (long)u*1040 + c;
    glo[o]=og[c*130+u]; ghi[o]=oh[c*130+u]; pho[o]=op[c*130+u];
  }
}

// F4: depthwise 3x3 over (u,v) + Y = amp*e^{i phase}
__global__ void k_four_dw(const float* glo, const float* ghi, const float* pho,
                          float* Yre, float* Yim,
                          const void* aldw, const void* ahdw, const int* flg){
  int bf=*flg;
  __shared__ float wl[144], wh[144];
  int t=threadIdx.x;
  if(t<144){wl[t]=LD(aldw,t,bf); wh[t]=LD(ahdw,t,bf);}
  __syncthreads();
  long o = (long)blockIdx.x*256+t;  // 532480 exact
  int c=(int)(o&15); long r=o>>4; int v=(int)(r%65); long r2=r/65; int u=(int)(r2&127); int b=(int)(r2>>7);
  float acc=0.f;
  for(int dp=0;dp<3;dp++){
    int uu=u-1+dp; if(uu<0||uu>=128) continue;
    for(int dq=0;dq<3;dq++){
      int vv=v-1+dq; if(vv<0||vv>=65) continue;
      long idx=(((long)(b*128+uu))*65+vv)*16+c;
      acc += wl[c*9+dp*3+dq]*glo[idx] + wh[c*9+dp*3+dq]*ghi[idx];
    }
  }
  float pvv = pho[o];
  float s_,c_; sincosf(pvv,&s_,&c_);
  Yre[o]=acc*c_; Yim[o]=acc*s_;
}

// I1: inverse col fft over u
__global__ void k_ifft_col(const float* Yre, const float* Yim, float* Zre, float* Zim){
  __shared__ float sre[2080], sim[2080];
  __shared__ float Ar[512], Ai[512];
  __shared__ float ct[128], st[128];
  int t=threadIdx.x;
  int b = blockIdx.x/65, v = blockIdx.x%65;
  MAKE_TWP(ct,st);
  long ibase = ((long)b*128)*1040 + v*16;
  for(int e=t;e<2048;e+=256){
    int u=e>>4, c=e&15;
    sre[c*130+u]=Yre[ibase + (long)u*1040 + c];
    sim[c*130+u]=Yim[ibase + (long)u*1040 + c];
  }
  __syncthreads();
  int w=t>>6, l=t&63, wb=w<<7;
  for(int c=w; c<16; c+=4){
    int sb=c*130;
    float x0r=sre[sb+l], x0i=sim[sb+l], x1r=sre[sb+64+l], x1i=sim[sb+64+l];
    int r0=rev7(l), r1=rev7(64+l);
    Ar[wb+r0]=x0r; Ai[wb+r0]=x0i;
    Ar[wb+r1]=x1r; Ai[wb+r1]=x1i;
    fft128(Ar+wb, Ai+wb, ct, st, l, +1.f);
    sre[sb+l]=Ar[wb+l]; sim[sb+l]=Ai[wb+l];
    sre[sb+64+l]=Ar[wb+64+l]; sim[sb+64+l]=Ai[wb+64+l];
  }
  __syncthreads();
  for(int e=t;e<2048;e+=256){
    int y=e>>4, c=e&15;
    Zre[ibase + (long)y*1040 + c]=sre[c*130+y];
    Zim[ibase + (long)y*1040 + c]=sim[c*130+y];
  }
}

// K3 merged: [0,256) ifft_row -> km | [256,6400) wave_dw -> g96
__global__ void k_mix2(const float* Zre, const float* Zim, float* km,
                       const float* m96, float* g96, const void* wdw_, const int* flg){
  __shared__ float smem[9664];
  int blk=blockIdx.x, t=threadIdx.x;
  if(blk<256){
    float* szre=smem; float* szim=smem+2112; float* oslab=smem+4224;
    float* Ar=smem+8384; float* Ai=smem+8896; float* ct=smem+9408; float* st=smem+9536;
    int b = blk>>6, y0 = (blk&63)<<1;
    MAKE_TWP(ct,st);
    long ibase = ((long)(b*128+y0))*1040;
    for(int e=t;e<2080;e+=256){
      int yl=e/1040, rem=e%1040, v=rem>>4, c=rem&15;
      szre[yl*1056 + c*66 + v]=Zre[ibase+e];
      szim[yl*1056 + c*66 + v]=Zim[ibase+e];
    }
    __syncthreads();
    int w=t>>6, l=t&63, wb=w<<7;
    const float inv=1.f/128.f;
    for(int li=w; li<32; li+=4){
      int yl=li>>4, c=li&15;
      int sb = yl*1056 + c*66;
      float zr0 = szre[sb+l];
      float zi0 = (l==0)?0.f:szim[sb+l];
      float zr1, zi1;
      if(l==0){ zr1=szre[sb+64]; zi1=0.f; }
      else    { zr1=szre[sb+64-l]; zi1=-szim[sb+64-l]; }
      int r0=rev7(l), r1=rev7(64+l);
      Ar[wb+r0]=zr0; Ai[wb+r0]=zi0;
      Ar[wb+r1]=zr1; Ai[wb+r1]=zi1;
      fft128(Ar+wb, Ai+wb, ct, st, l, +1.f);
      int ob = yl*2080 + c*130;
      oslab[ob+l]=Ar[wb+l]*inv;
      oslab[ob+64+l]=Ar[wb+64+l]*inv;
    }
    __syncthreads();
    long obase = ((long)(b*128+y0))*2048;
    for(int e=t;e<4096;e+=256){
      int yl=e>>11, rem=e&2047, x=rem>>4, c=rem&15;
      km[obase+e]=oslab[yl*2080 + c*130 + x];
    }
  } else {
    int bf=*flg;
    float* wdw=smem;  // 864
    for(int i=t;i<864;i+=256) wdw[i]=LD(wdw_,i,bf);
    __syncthreads();
    int o = (blk-256)*256+t;   // 1,572,864 exact
    int ch = o%96; int r = o/96; int px = r&4095; int b = r>>12;
    int i = px>>6, j = px&63;
    long mb = (long)b*393216;
    float acc=0.f;
    for(int dp=0;dp<3;dp++){ int ii=i-1+dp; if(ii<0||ii>=64) continue;
      for(int dq=0;dq<3;dq++){ int jj=j-1+dq; if(jj<0||jj>=64) continue;
        acc += wdw[ch*9+dp*3+dq]*m96[mb + (long)(ii*64+jj)*96 + ch]; } }
    g96[o]=geluf(acc);
  }
}

// A1: per-batch Gram matrices
__global__ void k_gram(const float* qm, const float* km, float* G){
  __shared__ float qs[256*16], ks[256*16];
  int b=blockIdx.x>>5; int chunk=blockIdx.x&31;
  int t=threadIdx.x; int r=t>>4, s=t&15;
  float akq=0.f, akk=0.f, aqq=0.f;
  for(int tile=0;tile<2;tile++){
    long pb=((long)b*HW + chunk*512 + tile*256)*16;
    for(int i=t;i<4096;i+=256){ qs[i]=qm[pb+i]; ks[i]=km[pb+i]; }
    __syncthreads();
    for(int p=0;p<256;p++){
      float kv=ks[p*16+r], qv=qs[p*16+s];
      akq += kv*qv;
      akk += kv*ks[p*16+s];
      aqq += qs[p*16+r]*qv;
    }
    __syncthreads();
  }
  float* Gb=G + b*768;
  atomicAdd(&Gb[t], akq);
  atomicAdd(&Gb[256+t], akk);
  atomicAdd(&Gb[512+t], aqq);
}

// A2: per (b,h): attn from Gram -> fold into M_b[16,64]
__global__ void k_attn(const float* G, float* Mb, const void* We,
                       const void* Wproj, const void* resc, const int* flg){
  int bf=*flg;
  __shared__ float wes[16*64];
  __shared__ float gkq[256], gkk[256], gqq[256];
  __shared__ float ukq[64*16], ukk[64*16], uqq[64*16];
  __shared__ float nk[64], nq[64];
  __shared__ float A[64*64];
  __shared__ float T[64*16];
  __shared__ float wpj[64*64];
  int b=blockIdx.x>>3, h=blockIdx.x&7;
  int t=threadIdx.x;
  for(int i=t;i<1024;i+=256){ int rr=i>>6, e=i&63; wes[rr*64+e]=LD(We, (long)rr*512 + h*64 + e, bf); }
  gkq[t]=G[b*768+t]; gkk[t]=G[b*768+256+t]; gqq[t]=G[b*768+512+t];
  for(int i=t;i<4096;i+=256){ int d=i>>6, c=i&63; wpj[i]=LD(Wproj,(long)(h*64+d)*64+c,bf); }
  __syncthreads();
  for(int i=t;i<1024;i+=256){
    int d=i>>4, s=i&15;
    float a1=0.f,a2=0.f,a3=0.f;
    for(int rr=0;rr<16;rr++){ float wv=wes[rr*64+d]; a1+=wv*gkq[rr*16+s]; a2+=wv*gkk[rr*16+s]; a3+=wv*gqq[rr*16+s]; }
    ukq[i]=a1; ukk[i]=a2; uqq[i]=a3;
  }
  __syncthreads();
  if(t<64){ float a=0.f; for(int s=0;s<16;s++) a+=ukk[t*16+s]*wes[s*64+t]; nk[t]=fmaxf(sqrtf(a),1e-12f); }
  else if(t<128){ int e=t-64; float a=0.f; for(int s=0;s<16;s++) a+=uqq[e*16+s]*wes[s*64+e]; nq[e]=fmaxf(sqrtf(a),1e-12f); }
  __syncthreads();
  float rsc=LD(resc,h,bf);
  for(int i=t;i<4096;i+=256){
    int d=i>>6, e=i&63;
    float a=0.f; for(int s=0;s<16;s++) a+=ukq[d*16+s]*wes[s*64+e];
    A[i]=a/(nk[d]*nq[e])*rsc;
  }
  __syncthreads();
  if(t<64){
    int d=t; float m=-1e30f;
    for(int e=0;e<64;e++) m=fmaxf(m,A[d*64+e]);
    float sum=0.f;
    for(int e=0;e<64;e++){ float ev=expf(A[d*64+e]-m); A[d*64+e]=ev; sum+=ev; }
    float inv=1.f/sum;
    for(int e=0;e<64;e++) A[d*64+e]*=inv;
  }
  __syncthreads();
  for(int i=t;i<1024;i+=256){
    int d=i>>4, s=i&15;
    float a=0.f; for(int e=0;e<64;e++) a+=A[d*64+e]*wes[s*64+e];
    T[i]=a;
  }
  __syncthreads();
  for(int i=t;i<1024;i+=256){
    int s=i>>6, c=i&63;
    float a=0.f; for(int d=0;d<64;d++) a+=T[d*16+s]*wpj[d*64+c];
    atomicAdd(&Mb[b*1024 + s*64 + c], a);
  }
}

// EPI: mlp_out(96->48) + residual haar + IWT + @M_b + bproj -> d_out
__global__ void k_epi(const float* g96, const float* vd, const float* Mb_,
                      const void* wout_, const void* rs_, const void* bproj,
                      void* out, const int* flg){
  int bf=*flg;
  __shared__ float wt[4608];
  __shared__ float gt[6144];
  __shared__ float he[4096];
  __shared__ float mb[1024];
  __shared__ float bias[64];
  int t=threadIdx.x;
  int b=blockIdx.x>>6; int tile=blockIdx.x&63;
  int i0=(tile>>3)<<3, j0=(tile&7)<<3;
  for(int i=t;i<4608;i+=256){ int ch=i/48, cc=i%48; wt[ch*48+cc]=LD(wout_,(long)cc*96+ch,bf); }
  for(int i=t;i<6144;i+=256){
    int px=i/96, ch=i%96;
    int gi=i0+(px>>3), gj=j0+(px&7);
    gt[i]=g96[((long)b*4096 + gi*64+gj)*96 + ch];
  }
  for(int i=t;i<1024;i+=256) mb[i]=Mb_[b*1024+i];
  if(t<64) bias[t]=LD(bproj,t,bf);
  __syncthreads();
  float rs=LD(rs_,0,bf);
  for(int o=t;o<3072;o+=256){
    int px=o/48, cc=o%48;
    int gi=i0+(px>>3), gj=j0+(px&7);
    float acc=0.f;
    for(int ch=0;ch<96;ch++) acc += wt[ch*48+cc]*gt[px*96+ch];
    long vb = ((long)(b*128+2*gi)*128 + 2*gj)*16;
    int m=cc+16, c=m>>2, f=m&3;
    float a=vd[vb+c], bv=vd[vb+16+c], cv=vd[vb+2048+c], dv=vd[vb+2048+16+c];
    float hv;
    if(f==0)      hv=(a+bv+cv+dv);
    else if(f==1) hv=(a-bv+cv-dv);
    else if(f==2) hv=(a+bv-cv-dv);
    else          hv=(a-bv-cv+dv);
    he[px*64 + 16 + cc] = hv*0.5f + rs*acc;
  }
  for(int o=t;o<1024;o+=256){
    int px=o>>4, c16=o&15;
    int gi=i0+(px>>3), gj=j0+(px&7);
    long vb=((long)(b*128+2*gi)*128+2*gj)*16;
    int c=c16>>2, f=c16&3;
    float a=vd[vb+c], bv=vd[vb+16+c], cv=vd[vb+2048+c], dv=vd[vb+2048+16+c];
    float hv;
    if(f==0)      hv=(a+bv+cv+dv);
    else if(f==1) hv=(a-bv+cv-dv);
    else if(f==2) hv=(a+bv-cv-dv);
    else          hv=(a-bv-cv+dv);
    he[px*64+c16]=hv*0.5f;
  }
  __syncthreads();
  for(int ok=t; ok<16384; ok+=256){
    int c=ok&63, px=ok>>6;
    int orow=px>>4, ocol=px&15;
    int halfpx=(orow>>1)*8 + (ocol>>1);
    int pos=((orow&1)<<1)|(ocol&1);
    const float* hv = he + halfpx*64 + pos*16;
    float acc=bias[c];
    for(int s=0;s<16;s++) acc += hv[s]*mb[s*64+c];
    long oo = (((long)(b*128 + 2*i0+orow))*128 + (2*j0+ocol))*64 + c;
    if(bf) ((__hip_bfloat16*)out)[oo]=__float2bfloat16(acc);
    else   ((float*)out)[oo]=acc;
  }
}

extern "C" void kernel_launch(void* const* d_in, const int* in_sizes, int n_in,
                              void* d_out, int out_size, void* d_ws, size_t ws_size,
                              hipStream_t stream) {
  const void* x_in   = d_in[0];
  const void* Wq     = d_in[1];
  const void* Wk     = d_in[2];
  const void* Wv     = d_in[3];
  const void* Wr     = d_in[4];
  const void* We     = d_in[5];
  const void* qs_dw  = d_in[6];
  const void* qs_pw  = d_in[7];
  const void* qs_g   = d_in[8];
  const void* al_pw  = d_in[9];
  const void* al_dw  = d_in[10];
  const void* ah_pw  = d_in[11];
  const void* ah_dw  = d_in[12];
  const void* ph_pw  = d_in[13];
  const void* ph_s   = d_in[14];
  const void* bn_g   = d_in[15];
  const void* bn_b   = d_in[16];
  const void* mlp_in = d_in[17];
  const void* mlp_dw = d_in[18];
  const void* mlp_out= d_in[19];
  const void* res_s  = d_in[20];
  const void* rescale= d_in[21];
  const void* Wproj  = d_in[22];
  const void* bproj  = d_in[23];
  float* ws = (float*)d_ws;
  const int* flg = ((const int*)ws) + OFF_FLAG;

  float* FA = ws + OFF_S;
  float* FB = FA + FSZ;
  float* FC = FB + FSZ;
  float* FD = FC + FSZ;
  float* FE = FD + FSZ;
  float* M96 = FE + FSZ;            // 1.5M floats
  float* G96 = ws + OFF_QDIM;       // overlays dead qd/kd (dead after k_mix3)

  k_head<<<49,256,0,stream>>>(Wq,Wk,Wv,Wr,bn_g, ws);
  k_dims<<<4096,256,0,stream>>>(x_in, ws, ws+OFF_QDIM, ws+OFF_KDIM, ws+OFF_VDIM, flg);
  // spatial(q) || fft_row(k) || wave_a(v)
  k_mix3<<<1536,256,0,stream>>>(ws+OFF_QDIM, ws+OFF_QMIX, qs_dw, qs_pw, qs_g,
                                ws+OFF_KDIM, FA, FB,
                                ws+OFF_VDIM, M96, mlp_in, bn_g, bn_b, flg);
  k_fft_col<<<260,256,0,stream>>>(FA, FB, FC, FD, FE, al_pw, ah_pw, ph_pw, ph_s, flg);
  k_four_dw<<<2080,256,0,stream>>>(FC, FD, FE, FA, FB, al_dw, ah_dw, flg);
  k_ifft_col<<<260,256,0,stream>>>(FA, FB, FC, FD);
  // ifft_row(k) || wave_dw(v)
  k_mix2<<<6400,256,0,stream>>>(FC, FD, ws+OFF_KMIX, M96, G96, mlp_dw, flg);
  k_gram<<<128,256,0,stream>>>(ws+OFF_QMIX, ws+OFF_KMIX, ws+OFF_G);
  k_attn<<<32,256,0,stream>>>(ws+OFF_G, ws+OFF_MB, We, Wproj, rescale, flg);
  k_epi<<<256,256,0,stream>>>(G96, ws+OFF_VDIM, ws+OFF_MB, mlp_out, res_s, bproj, d_out, flg);
}